// Round 1
// baseline (3958.545 us; speedup 1.0000x reference)
//
#include <hip/hip_runtime.h>
#include <math.h>

// Problem dims (fixed by reference)
#define C_DIM 256      // h width
#define HID 128
#define HEADS 4
#define OC 64          // per-head out channels
#define FF_DIM 512
#define NLAYERS 12

constexpr float LN_EPS = 1e-5f;
constexpr float SLOPE  = 0.2f;

__device__ __forceinline__ float leaky(float x) { return x > 0.f ? x : SLOPE * x; }

// ---------------------------------------------------------------------------
// Small utility kernels
// ---------------------------------------------------------------------------
__global__ void zero_i32_kernel(int* __restrict__ p, int n) {
    int i = blockIdx.x * blockDim.x + threadIdx.x;
    if (i < n) p[i] = 0;
}

__global__ void concat_kernel(const float* __restrict__ hf, const float* __restrict__ hs,
                              float* __restrict__ h, int Nn) {
    int idx = blockIdx.x * blockDim.x + threadIdx.x;
    int total = Nn * C_DIM;
    if (idx < total) {
        int n = idx >> 8;       // /256
        int c = idx & 255;
        h[idx] = (c < HID) ? hf[n * HID + c] : hs[n * HID + (c - HID)];
    }
}

__global__ void split_kernel(const float* __restrict__ h, float* __restrict__ out, int Nn) {
    int idx = blockIdx.x * blockDim.x + threadIdx.x;
    int total = Nn * HID;
    if (idx < total) {
        int n = idx / HID;
        int c = idx - n * HID;
        out[idx]         = h[n * C_DIM + c];
        out[total + idx] = h[n * C_DIM + HID + c];
    }
}

// ---------------------------------------------------------------------------
// CSR build: histogram of dst, exclusive scan, fill src lists
// ---------------------------------------------------------------------------
__global__ void hist_kernel(const int* __restrict__ dst, int* __restrict__ counts, int E) {
    int e = blockIdx.x * blockDim.x + threadIdx.x;
    if (e < E) atomicAdd(&counts[dst[e]], 1);
}

// single block, 1024 threads: exclusive scan of counts[0..n) -> offsets[0..n], cursor copy
__global__ void scan_kernel(const int* __restrict__ counts, int* __restrict__ offsets,
                            int* __restrict__ cursor, int n) {
    __shared__ int sdata[1024];
    __shared__ int carry;
    if (threadIdx.x == 0) carry = 0;
    __syncthreads();
    for (int base = 0; base < n; base += 1024) {
        int i = base + (int)threadIdx.x;
        int v = (i < n) ? counts[i] : 0;
        sdata[threadIdx.x] = v;
        __syncthreads();
        for (int off = 1; off < 1024; off <<= 1) {
            int t = (threadIdx.x >= (unsigned)off) ? sdata[threadIdx.x - off] : 0;
            __syncthreads();
            sdata[threadIdx.x] += t;
            __syncthreads();
        }
        int incl = sdata[threadIdx.x];
        int excl = incl - v;
        if (i < n) {
            offsets[i] = carry + excl;
            cursor[i]  = carry + excl;
        }
        __syncthreads();
        if (threadIdx.x == 1023) carry += sdata[1023];
        __syncthreads();
    }
    if (threadIdx.x == 0) offsets[n] = carry;
}

__global__ void fill_kernel(const int* __restrict__ src, const int* __restrict__ dst,
                            int* __restrict__ cursor, int* __restrict__ csr_src, int E) {
    int e = blockIdx.x * blockDim.x + threadIdx.x;
    if (e < E) {
        int d = dst[e];
        int p = atomicAdd(&cursor[d], 1);
        csr_src[p] = src[e];
    }
}

// ---------------------------------------------------------------------------
// Tiled fp32 GEMM: C = op(A[MxK] @ B[KxN] + bias), optional ReLU.
// 64x64 tile, BK=16, 256 threads, 4x4 per thread.
// ---------------------------------------------------------------------------
#define TM 64
#define TN 64
#define TK 16
#define APAD 68   // row stride (floats) of transposed A tile: 68*4=272 bytes, 16B aligned

__global__ __launch_bounds__(256) void gemm_kernel(
    const float* __restrict__ A, const float* __restrict__ B,
    const float* __restrict__ bias, float* __restrict__ Cmat,
    int M, int N, int K, int fuse_relu)
{
    __shared__ float As[TK * APAD];   // As[k][m], padded
    __shared__ float Bs[TK * TN];     // Bs[k][n]

    const int tid = threadIdx.x;
    const int tx = tid & 15;          // 0..15 -> col group
    const int ty = tid >> 4;          // 0..15 -> row group
    const int row0 = blockIdx.x * TM;
    const int col0 = blockIdx.y * TN;

    // A load mapping: one float4 per thread. arow 0..63, acol 0,4,8,12
    const int arow = tid >> 2;
    const int acol = (tid & 3) * 4;
    // B load mapping: one float4 per thread. brow 0..15, bcol 0..60
    const int brow = tid >> 4;
    const int bcol = (tid & 15) * 4;

    float acc[4][4] = {};

    const int numk = K / TK;
    for (int kt = 0; kt < numk; ++kt) {
        const int k0 = kt * TK;
        // Load A tile (transposed into LDS): As[k][m]
        float4 av;
        int ar = row0 + arow;
        if (ar < M) av = *(const float4*)&A[(size_t)ar * K + k0 + acol];
        else        av = make_float4(0.f, 0.f, 0.f, 0.f);
        As[(acol + 0) * APAD + arow] = av.x;
        As[(acol + 1) * APAD + arow] = av.y;
        As[(acol + 2) * APAD + arow] = av.z;
        As[(acol + 3) * APAD + arow] = av.w;
        // Load B tile
        float4 bv = *(const float4*)&B[(size_t)(k0 + brow) * N + col0 + bcol];
        *(float4*)&Bs[brow * TN + bcol] = bv;
        __syncthreads();

        #pragma unroll
        for (int k = 0; k < TK; ++k) {
            float4 a4 = *(const float4*)&As[k * APAD + ty * 4];
            float4 b4 = *(const float4*)&Bs[k * TN + tx * 4];
            float a[4] = {a4.x, a4.y, a4.z, a4.w};
            float b[4] = {b4.x, b4.y, b4.z, b4.w};
            #pragma unroll
            for (int m = 0; m < 4; ++m)
                #pragma unroll
                for (int n = 0; n < 4; ++n)
                    acc[m][n] += a[m] * b[n];
        }
        __syncthreads();
    }

    // Epilogue
    float4 bias4 = make_float4(0.f, 0.f, 0.f, 0.f);
    if (bias) bias4 = *(const float4*)&bias[col0 + tx * 4];
    #pragma unroll
    for (int m = 0; m < 4; ++m) {
        int r = row0 + ty * 4 + m;
        if (r >= M) continue;
        float4 v;
        v.x = acc[m][0] + bias4.x;
        v.y = acc[m][1] + bias4.y;
        v.z = acc[m][2] + bias4.z;
        v.w = acc[m][3] + bias4.w;
        if (fuse_relu) {
            v.x = fmaxf(v.x, 0.f); v.y = fmaxf(v.y, 0.f);
            v.z = fmaxf(v.z, 0.f); v.w = fmaxf(v.w, 0.f);
        }
        *(float4*)&Cmat[(size_t)r * N + col0 + tx * 4] = v;
    }
}

// ---------------------------------------------------------------------------
// Attention coefficients: a_s[n,h] = sum_oc xh[n,h,oc]*att_src[h,oc]; same a_d
// one block (256 thr) per node; wave per head.
// ---------------------------------------------------------------------------
__global__ __launch_bounds__(256) void attn_kernel(
    const float* __restrict__ xh, const float* __restrict__ att_s,
    const float* __restrict__ att_d, float* __restrict__ a_s, float* __restrict__ a_d)
{
    int n = blockIdx.x;
    int tid = threadIdx.x;
    int head = tid >> 6;
    int lane = tid & 63;
    float x = xh[n * C_DIM + tid];
    float vs = x * att_s[tid];
    float vd = x * att_d[tid];
    #pragma unroll
    for (int off = 32; off > 0; off >>= 1) {
        vs += __shfl_down(vs, off);
        vd += __shfl_down(vd, off);
    }
    if (lane == 0) {
        a_s[n * HEADS + head] = vs;
        a_d[n * HEADS + head] = vd;
    }
}

// ---------------------------------------------------------------------------
// Fused GAT aggregation (online segment-softmax incl self-loop) + bias +
// residual + LayerNorm. One block (256 thr) per node; wave per head.
// h updated in place.
// ---------------------------------------------------------------------------
__global__ __launch_bounds__(256) void gat_kernel(
    const float* __restrict__ xh, const float* __restrict__ a_s,
    const float* __restrict__ a_d, const int* __restrict__ csr_src,
    const int* __restrict__ offs, const float* __restrict__ gat_b,
    const float* __restrict__ ln_g, const float* __restrict__ ln_b,
    float* __restrict__ h)
{
    int n = blockIdx.x;
    int tid = threadIdx.x;
    int head = tid >> 6;
    int lane = tid & 63;

    float ad = a_d[n * HEADS + head];
    // self-loop edge
    float e0 = leaky(a_s[n * HEADS + head] + ad);
    float m = e0;
    float l = 1.0f;
    float acc = xh[n * C_DIM + tid];   // weight exp(e0-m)=1

    int beg = offs[n], end = offs[n + 1];
    for (int i = beg; i < end; ++i) {
        int s = csr_src[i];
        float e = leaky(a_s[s * HEADS + head] + ad);
        float xv = xh[s * C_DIM + tid];   // tid == head*64+lane
        if (e <= m) {
            float w = __expf(e - m);
            l += w;
            acc += w * xv;
        } else {
            float r = __expf(m - e);
            l = l * r + 1.0f;
            acc = acc * r + xv;
            m = e;
        }
    }

    float val = acc / l + gat_b[tid] + h[n * C_DIM + tid];

    // Block LayerNorm over 256 channels
    __shared__ float ws1[HEADS], ws2[HEADS];
    float s1 = val, s2 = val * val;
    #pragma unroll
    for (int off = 32; off > 0; off >>= 1) {
        s1 += __shfl_down(s1, off);
        s2 += __shfl_down(s2, off);
    }
    if (lane == 0) { ws1[head] = s1; ws2[head] = s2; }
    __syncthreads();
    float mean = (ws1[0] + ws1[1] + ws1[2] + ws1[3]) * (1.0f / C_DIM);
    float msq  = (ws2[0] + ws2[1] + ws2[2] + ws2[3]) * (1.0f / C_DIM);
    float var = msq - mean * mean;
    float inv = rsqrtf(var + LN_EPS);
    h[n * C_DIM + tid] = (val - mean) * inv * ln_g[tid] + ln_b[tid];
}

// ---------------------------------------------------------------------------
// ln2: h = LN(fbuf + h) * g + b  (in place), block per node
// ---------------------------------------------------------------------------
__global__ __launch_bounds__(256) void ln2_kernel(
    const float* __restrict__ fbuf, const float* __restrict__ ln_g,
    const float* __restrict__ ln_b, float* __restrict__ h)
{
    int n = blockIdx.x;
    int tid = threadIdx.x;
    int head = tid >> 6;
    int lane = tid & 63;

    float val = fbuf[n * C_DIM + tid] + h[n * C_DIM + tid];

    __shared__ float ws1[HEADS], ws2[HEADS];
    float s1 = val, s2 = val * val;
    #pragma unroll
    for (int off = 32; off > 0; off >>= 1) {
        s1 += __shfl_down(s1, off);
        s2 += __shfl_down(s2, off);
    }
    if (lane == 0) { ws1[head] = s1; ws2[head] = s2; }
    __syncthreads();
    float mean = (ws1[0] + ws1[1] + ws1[2] + ws1[3]) * (1.0f / C_DIM);
    float msq  = (ws2[0] + ws2[1] + ws2[2] + ws2[3]) * (1.0f / C_DIM);
    float var = msq - mean * mean;
    float inv = rsqrtf(var + LN_EPS);
    h[n * C_DIM + tid] = (val - mean) * inv * ln_g[tid] + ln_b[tid];
}

// ---------------------------------------------------------------------------
// Host launch
// ---------------------------------------------------------------------------
extern "C" void kernel_launch(void* const* d_in, const int* in_sizes, int n_in,
                              void* d_out, int out_size, void* d_ws, size_t ws_size,
                              hipStream_t stream)
{
    const float* hf       = (const float*)d_in[0];
    const float* hs       = (const float*)d_in[1];
    const int*   edge     = (const int*)  d_in[2];
    const float* W        = (const float*)d_in[3];
    const float* att_src  = (const float*)d_in[4];
    const float* att_dst  = (const float*)d_in[5];
    const float* gat_b    = (const float*)d_in[6];
    const float* w1       = (const float*)d_in[7];
    const float* b1       = (const float*)d_in[8];
    const float* w2       = (const float*)d_in[9];
    const float* b2       = (const float*)d_in[10];
    const float* ln1g     = (const float*)d_in[11];
    const float* ln1b     = (const float*)d_in[12];
    const float* ln2g     = (const float*)d_in[13];
    const float* ln2b     = (const float*)d_in[14];
    float* out = (float*)d_out;

    const int N = in_sizes[0] / HID;       // 20000
    const int E = in_sizes[2] / 2;         // 320000
    const int* e_src = edge;
    const int* e_dst = edge + E;

    // Workspace carve-up (256B aligned)
    char* p = (char*)d_ws;
    auto alloc = [&](size_t bytes) {
        char* r = p;
        p += (bytes + 255) & ~(size_t)255;
        return (void*)r;
    };
    float* h      = (float*)alloc((size_t)N * C_DIM * 4);
    float* xh     = (float*)alloc((size_t)N * C_DIM * 4);   // also reused as FFN out buf
    float* mid    = (float*)alloc((size_t)N * FF_DIM * 4);
    float* a_s    = (float*)alloc((size_t)N * HEADS * 4);
    float* a_d    = (float*)alloc((size_t)N * HEADS * 4);
    int*   counts = (int*)alloc((size_t)N * 4);
    int*   offs   = (int*)alloc((size_t)(N + 1) * 4);
    int*   cursor = (int*)alloc((size_t)N * 4);
    int*   csr    = (int*)alloc((size_t)E * 4);

    // h = concat(hf, hs)
    {
        int total = N * C_DIM;
        concat_kernel<<<(total + 255) / 256, 256, 0, stream>>>(hf, hs, h, N);
    }
    // CSR build
    zero_i32_kernel<<<(N + 255) / 256, 256, 0, stream>>>(counts, N);
    hist_kernel<<<(E + 255) / 256, 256, 0, stream>>>(e_dst, counts, E);
    scan_kernel<<<1, 1024, 0, stream>>>(counts, offs, cursor, N);
    fill_kernel<<<(E + 255) / 256, 256, 0, stream>>>(e_src, e_dst, cursor, csr, E);

    const int gm = (N + TM - 1) / TM;   // 313

    for (int l = 0; l < NLAYERS; ++l) {
        const float* Wl   = W + (size_t)l * C_DIM * C_DIM;
        const float* asl  = att_src + (size_t)l * C_DIM;  // [H,OC] flat = 256
        const float* adl  = att_dst + (size_t)l * C_DIM;
        const float* gbl  = gat_b + (size_t)l * C_DIM;
        const float* w1l  = w1 + (size_t)l * C_DIM * FF_DIM;
        const float* b1l  = b1 + (size_t)l * FF_DIM;
        const float* w2l  = w2 + (size_t)l * FF_DIM * C_DIM;
        const float* b2l  = b2 + (size_t)l * C_DIM;
        const float* g1l  = ln1g + (size_t)l * C_DIM;
        const float* be1l = ln1b + (size_t)l * C_DIM;
        const float* g2l  = ln2g + (size_t)l * C_DIM;
        const float* be2l = ln2b + (size_t)l * C_DIM;

        // xh = h @ W[l]
        gemm_kernel<<<dim3(gm, C_DIM / TN), 256, 0, stream>>>(h, Wl, nullptr, xh,
                                                              N, C_DIM, C_DIM, 0);
        // attention coefficients
        attn_kernel<<<N, 256, 0, stream>>>(xh, asl, adl, a_s, a_d);
        // fused GAT + residual + LN1 (h in place)
        gat_kernel<<<N, 256, 0, stream>>>(xh, a_s, a_d, csr, offs, gbl, g1l, be1l, h);
        // mid = relu(h @ w1 + b1)
        gemm_kernel<<<dim3(gm, FF_DIM / TN), 256, 0, stream>>>(h, w1l, b1l, mid,
                                                               N, FF_DIM, C_DIM, 1);
        // xh (reuse) = mid @ w2 + b2
        gemm_kernel<<<dim3(gm, C_DIM / TN), 256, 0, stream>>>(mid, w2l, b2l, xh,
                                                              N, C_DIM, FF_DIM, 0);
        // h = LN(xh + h)
        ln2_kernel<<<N, 256, 0, stream>>>(xh, g2l, be2l, h);
    }

    // split h -> out
    {
        int total = N * HID;
        split_kernel<<<(total + 255) / 256, 256, 0, stream>>>(h, out, N);
    }
}

// Round 2
// 2058.454 us; speedup vs baseline: 1.9231x; 1.9231x over previous
//
#include <hip/hip_runtime.h>
#include <hip/hip_bf16.h>
#include <math.h>

// Problem dims (fixed by reference)
#define C_DIM 256      // h width
#define HID 128
#define HEADS 4
#define OC 64          // per-head out channels
#define FF_DIM 512
#define NLAYERS 12

constexpr float LN_EPS = 1e-5f;
constexpr float SLOPE  = 0.2f;

typedef __attribute__((ext_vector_type(4))) float f32x4;
typedef __attribute__((ext_vector_type(8))) short bf16x8_t;
typedef __attribute__((ext_vector_type(4))) int i32x4;

__device__ __forceinline__ float leaky(float x) { return x > 0.f ? x : SLOPE * x; }

// ---------------------------------------------------------------------------
// Small utility kernels
// ---------------------------------------------------------------------------
__global__ void zero_i32_kernel(int* __restrict__ p, int n) {
    int i = blockIdx.x * blockDim.x + threadIdx.x;
    if (i < n) p[i] = 0;
}

__global__ void concat_kernel(const float* __restrict__ hf, const float* __restrict__ hs,
                              float* __restrict__ h, __hip_bfloat16* __restrict__ hb, int Nn) {
    int idx = blockIdx.x * blockDim.x + threadIdx.x;
    int total = Nn * C_DIM;
    if (idx < total) {
        int n = idx >> 8;
        int c = idx & 255;
        float v = (c < HID) ? hf[n * HID + c] : hs[n * HID + (c - HID)];
        h[idx] = v;
        hb[idx] = __float2bfloat16(v);
    }
}

__global__ void split_kernel(const float* __restrict__ h, float* __restrict__ out, int Nn) {
    int idx = blockIdx.x * blockDim.x + threadIdx.x;
    int total = Nn * HID;
    if (idx < total) {
        int n = idx / HID;
        int c = idx - n * HID;
        out[idx]         = h[n * C_DIM + c];
        out[total + idx] = h[n * C_DIM + HID + c];
    }
}

// Transpose + convert weights: in [L][K][N] fp32 -> out [L][N][K] bf16
__global__ void transp_bf16_kernel(const float* __restrict__ in,
                                   __hip_bfloat16* __restrict__ out, int K, int N) {
    __shared__ float t[32][33];
    const float* inl = in + (size_t)blockIdx.z * K * N;
    __hip_bfloat16* outl = out + (size_t)blockIdx.z * K * N;
    int kb = blockIdx.y * 32, nb = blockIdx.x * 32;
    int tx = threadIdx.x & 31, ty = threadIdx.x >> 5; // 32x8
    #pragma unroll
    for (int r = 0; r < 32; r += 8)
        t[ty + r][tx] = inl[(size_t)(kb + ty + r) * N + nb + tx];
    __syncthreads();
    #pragma unroll
    for (int r = 0; r < 32; r += 8)
        outl[(size_t)(nb + ty + r) * K + kb + tx] = __float2bfloat16(t[tx][ty + r]);
}

// ---------------------------------------------------------------------------
// CSR build: histogram of dst, exclusive scan, fill src lists
// ---------------------------------------------------------------------------
__global__ void hist_kernel(const int* __restrict__ dst, int* __restrict__ counts, int E) {
    int e = blockIdx.x * blockDim.x + threadIdx.x;
    if (e < E) atomicAdd(&counts[dst[e]], 1);
}

__global__ void scan_kernel(const int* __restrict__ counts, int* __restrict__ offsets,
                            int* __restrict__ cursor, int n) {
    __shared__ int sdata[1024];
    __shared__ int carry;
    if (threadIdx.x == 0) carry = 0;
    __syncthreads();
    for (int base = 0; base < n; base += 1024) {
        int i = base + (int)threadIdx.x;
        int v = (i < n) ? counts[i] : 0;
        sdata[threadIdx.x] = v;
        __syncthreads();
        for (int off = 1; off < 1024; off <<= 1) {
            int t = (threadIdx.x >= (unsigned)off) ? sdata[threadIdx.x - off] : 0;
            __syncthreads();
            sdata[threadIdx.x] += t;
            __syncthreads();
        }
        int incl = sdata[threadIdx.x];
        int excl = incl - v;
        if (i < n) {
            offsets[i] = carry + excl;
            cursor[i]  = carry + excl;
        }
        __syncthreads();
        if (threadIdx.x == 1023) carry += sdata[1023];
        __syncthreads();
    }
    if (threadIdx.x == 0) offsets[n] = carry;
}

__global__ void fill_kernel(const int* __restrict__ src, const int* __restrict__ dst,
                            int* __restrict__ cursor, int* __restrict__ csr_src, int E) {
    int e = blockIdx.x * blockDim.x + threadIdx.x;
    if (e < E) {
        int d = dst[e];
        int p = atomicAdd(&cursor[d], 1);
        csr_src[p] = src[e];
    }
}

// ---------------------------------------------------------------------------
// bf16 MFMA GEMM: C = op(A[MxK]_bf16 @ (BT[NxK]_bf16)^T + bias)
// 128x128 tile, BK=32, 256 threads (4 waves, 2x2), 4x4 MFMA 16x16x32 per wave.
// A-frag: A[m=lane&15][k=(lane>>4)*8+j]; B-frag: B[k=(lane>>4)*8+j][n=lane&15]
// C/D:    col=lane&15, row=(lane>>4)*4+reg  [verified m89/m91]
// ---------------------------------------------------------------------------
#define BM 128
#define BN 128
#define BK 32
#define LSTR 40   // LDS row stride (shorts): 80B, 16B-aligned, ~2-way bank alias (free)

__global__ __launch_bounds__(256) void gemm_bf16_kernel(
    const __hip_bfloat16* __restrict__ A,   // [M x K] bf16 row-major
    const __hip_bfloat16* __restrict__ BT,  // [N x K] bf16 row-major (B^T)
    const float* __restrict__ bias,         // [N] or null
    float* __restrict__ Cf,                 // fp32 out or null
    __hip_bfloat16* __restrict__ Cb,        // bf16 out or null
    int M, int N, int K, int relu)
{
    __shared__ short As[BM * LSTR];
    __shared__ short Bs[BN * LSTR];
    const int tid = threadIdx.x;
    const int wave = tid >> 6, lane = tid & 63;
    const int lr = lane & 15, lq = lane >> 4;
    const int wm = (wave >> 1) * 64, wn = (wave & 1) * 64;
    const int row0 = blockIdx.x * BM, col0 = blockIdx.y * BN;

    // staging: each thread loads 2 16B chunks of A and 2 of B
    const int r0 = tid >> 2;              // 0..63
    const int kc0 = (tid & 3) * 8;        // 0,8,16,24

    f32x4 acc[4][4] = {};

    for (int k0 = 0; k0 < K; k0 += BK) {
        int gr = row0 + r0;
        i32x4 va = {};
        if (gr < M) va = *(const i32x4*)&A[(size_t)gr * K + k0 + kc0];
        *(i32x4*)&As[r0 * LSTR + kc0] = va;
        gr = row0 + r0 + 64;
        i32x4 va2 = {};
        if (gr < M) va2 = *(const i32x4*)&A[(size_t)gr * K + k0 + kc0];
        *(i32x4*)&As[(r0 + 64) * LSTR + kc0] = va2;
        i32x4 vb = *(const i32x4*)&BT[(size_t)(col0 + r0) * K + k0 + kc0];
        *(i32x4*)&Bs[r0 * LSTR + kc0] = vb;
        i32x4 vb2 = *(const i32x4*)&BT[(size_t)(col0 + r0 + 64) * K + k0 + kc0];
        *(i32x4*)&Bs[(r0 + 64) * LSTR + kc0] = vb2;
        __syncthreads();

        bf16x8_t afrag[4], bfrag[4];
        #pragma unroll
        for (int t = 0; t < 4; ++t) {
            afrag[t] = *(const bf16x8_t*)&As[(wm + t * 16 + lr) * LSTR + lq * 8];
            bfrag[t] = *(const bf16x8_t*)&Bs[(wn + t * 16 + lr) * LSTR + lq * 8];
        }
        #pragma unroll
        for (int mt = 0; mt < 4; ++mt)
            #pragma unroll
            for (int nt = 0; nt < 4; ++nt)
                acc[mt][nt] = __builtin_amdgcn_mfma_f32_16x16x32_bf16(
                    afrag[mt], bfrag[nt], acc[mt][nt], 0, 0, 0);
        __syncthreads();
    }

    float bv[4];
    #pragma unroll
    for (int nt = 0; nt < 4; ++nt)
        bv[nt] = bias ? bias[col0 + wn + nt * 16 + lr] : 0.f;

    #pragma unroll
    for (int mt = 0; mt < 4; ++mt) {
        #pragma unroll
        for (int r = 0; r < 4; ++r) {
            int grow = row0 + wm + mt * 16 + lq * 4 + r;
            if (grow >= M) continue;
            #pragma unroll
            for (int nt = 0; nt < 4; ++nt) {
                float v = acc[mt][nt][r] + bv[nt];
                if (relu) v = fmaxf(v, 0.f);
                int gcol = col0 + wn + nt * 16 + lr;
                if (Cf) Cf[(size_t)grow * N + gcol] = v;
                if (Cb) Cb[(size_t)grow * N + gcol] = __float2bfloat16(v);
            }
        }
    }
}

// ---------------------------------------------------------------------------
// Attention coefficients: a_s[n,h], a_d[n,h]
// ---------------------------------------------------------------------------
__global__ __launch_bounds__(256) void attn_kernel(
    const float* __restrict__ xh, const float* __restrict__ att_s,
    const float* __restrict__ att_d, float* __restrict__ a_s, float* __restrict__ a_d)
{
    int n = blockIdx.x;
    int tid = threadIdx.x;
    int head = tid >> 6;
    int lane = tid & 63;
    float x = xh[n * C_DIM + tid];
    float vs = x * att_s[tid];
    float vd = x * att_d[tid];
    #pragma unroll
    for (int off = 32; off > 0; off >>= 1) {
        vs += __shfl_down(vs, off);
        vd += __shfl_down(vd, off);
    }
    if (lane == 0) {
        a_s[n * HEADS + head] = vs;
        a_d[n * HEADS + head] = vd;
    }
}

// ---------------------------------------------------------------------------
// Per-edge softmax weights: one wave per node, lanes parallel over in-edges.
// ebuf[e][h]: pass1 stores e-values, final pass overwrites with normalized alpha.
// selfw[n][h] = normalized self-loop weight.
// ---------------------------------------------------------------------------
__global__ __launch_bounds__(256) void alpha_kernel(
    const float* __restrict__ a_s, const float* __restrict__ a_d,
    const int* __restrict__ csr, const int* __restrict__ offs,
    float* __restrict__ ebuf, float* __restrict__ selfw, int Nn)
{
    int n = blockIdx.x * 4 + (threadIdx.x >> 6);
    int lane = threadIdx.x & 63;
    if (n >= Nn) return;
    int beg = offs[n], end = offs[n + 1];

    float4 adv = *(const float4*)&a_d[(size_t)n * 4];
    float4 asv = *(const float4*)&a_s[(size_t)n * 4];
    const float ad[4] = {adv.x, adv.y, adv.z, adv.w};
    const float as0[4] = {asv.x, asv.y, asv.z, asv.w};
    float e0[4], m[4];
    #pragma unroll
    for (int h = 0; h < 4; ++h) { e0[h] = leaky(as0[h] + ad[h]); m[h] = e0[h]; }

    // pass 1: e-values + running max
    for (int i = beg + lane; i < end; i += 64) {
        int s = csr[i];
        float4 av = *(const float4*)&a_s[(size_t)s * 4];
        float sa[4] = {av.x, av.y, av.z, av.w};
        float e[4];
        #pragma unroll
        for (int h = 0; h < 4; ++h) {
            e[h] = leaky(sa[h] + ad[h]);
            m[h] = fmaxf(m[h], e[h]);
        }
        float4 ev = {e[0], e[1], e[2], e[3]};
        *(float4*)&ebuf[(size_t)i * 4] = ev;
    }
    #pragma unroll
    for (int off = 1; off < 64; off <<= 1) {
        #pragma unroll
        for (int h = 0; h < 4; ++h) m[h] = fmaxf(m[h], __shfl_xor(m[h], off));
    }

    // pass 2: sum of exp
    float l[4] = {0.f, 0.f, 0.f, 0.f};
    for (int i = beg + lane; i < end; i += 64) {
        float4 ev = *(const float4*)&ebuf[(size_t)i * 4];
        float e[4] = {ev.x, ev.y, ev.z, ev.w};
        #pragma unroll
        for (int h = 0; h < 4; ++h) l[h] += __expf(e[h] - m[h]);
    }
    #pragma unroll
    for (int off = 1; off < 64; off <<= 1) {
        #pragma unroll
        for (int h = 0; h < 4; ++h) l[h] += __shfl_xor(l[h], off);
    }
    float rinv[4], sw[4];
    #pragma unroll
    for (int h = 0; h < 4; ++h) {
        sw[h] = __expf(e0[h] - m[h]);          // self-loop exp
        rinv[h] = 1.0f / (l[h] + sw[h]);       // z includes self term
    }
    if (lane == 0) {
        float4 s4 = {sw[0] * rinv[0], sw[1] * rinv[1], sw[2] * rinv[2], sw[3] * rinv[3]};
        *(float4*)&selfw[(size_t)n * 4] = s4;
    }
    // pass 3: normalized alpha
    for (int i = beg + lane; i < end; i += 64) {
        float4 ev = *(const float4*)&ebuf[(size_t)i * 4];
        float e[4] = {ev.x, ev.y, ev.z, ev.w};
        float a[4];
        #pragma unroll
        for (int h = 0; h < 4; ++h) a[h] = __expf(e[h] - m[h]) * rinv[h];
        float4 av = {a[0], a[1], a[2], a[3]};
        *(float4*)&ebuf[(size_t)i * 4] = av;
    }
}

// ---------------------------------------------------------------------------
// Weighted aggregation + bias + residual + LN. Block (256) per node.
// ---------------------------------------------------------------------------
__global__ __launch_bounds__(256) void agg_kernel(
    const float* __restrict__ xh, const float* __restrict__ alpha,
    const float* __restrict__ selfw, const int* __restrict__ csr,
    const int* __restrict__ offs, const float* __restrict__ gat_b,
    const float* __restrict__ ln_g, const float* __restrict__ ln_b,
    float* __restrict__ h, __hip_bfloat16* __restrict__ hb)
{
    int n = blockIdx.x;
    int tid = threadIdx.x;
    int head = tid >> 6;
    int lane = tid & 63;

    float acc0 = selfw[n * HEADS + head] * xh[(size_t)n * C_DIM + tid];
    float acc1 = 0.f, acc2 = 0.f, acc3 = 0.f;
    int beg = offs[n], end = offs[n + 1];
    int i = beg;
    for (; i + 4 <= end; i += 4) {
        int s0 = csr[i], s1 = csr[i + 1], s2 = csr[i + 2], s3 = csr[i + 3];
        float w0 = alpha[(size_t)i * 4 + head];
        float w1 = alpha[(size_t)(i + 1) * 4 + head];
        float w2 = alpha[(size_t)(i + 2) * 4 + head];
        float w3 = alpha[(size_t)(i + 3) * 4 + head];
        acc0 += w0 * xh[(size_t)s0 * C_DIM + tid];
        acc1 += w1 * xh[(size_t)s1 * C_DIM + tid];
        acc2 += w2 * xh[(size_t)s2 * C_DIM + tid];
        acc3 += w3 * xh[(size_t)s3 * C_DIM + tid];
    }
    for (; i < end; ++i)
        acc0 += alpha[(size_t)i * 4 + head] * xh[(size_t)csr[i] * C_DIM + tid];

    float val = ((acc0 + acc1) + (acc2 + acc3)) + gat_b[tid] + h[(size_t)n * C_DIM + tid];

    __shared__ float ws1[HEADS], ws2[HEADS];
    float s1 = val, s2 = val * val;
    #pragma unroll
    for (int off = 32; off > 0; off >>= 1) {
        s1 += __shfl_down(s1, off);
        s2 += __shfl_down(s2, off);
    }
    if (lane == 0) { ws1[head] = s1; ws2[head] = s2; }
    __syncthreads();
    float mean = (ws1[0] + ws1[1] + ws1[2] + ws1[3]) * (1.0f / C_DIM);
    float msq  = (ws2[0] + ws2[1] + ws2[2] + ws2[3]) * (1.0f / C_DIM);
    float var = msq - mean * mean;
    float inv = rsqrtf(var + LN_EPS);
    float o = (val - mean) * inv * ln_g[tid] + ln_b[tid];
    h[(size_t)n * C_DIM + tid] = o;
    hb[(size_t)n * C_DIM + tid] = __float2bfloat16(o);
}

// ---------------------------------------------------------------------------
// ln2: h = LN(fbuf + h); writes fp32 h and bf16 hb
// ---------------------------------------------------------------------------
__global__ __launch_bounds__(256) void ln2_kernel(
    const float* __restrict__ fbuf, const float* __restrict__ ln_g,
    const float* __restrict__ ln_b, float* __restrict__ h,
    __hip_bfloat16* __restrict__ hb)
{
    int n = blockIdx.x;
    int tid = threadIdx.x;
    int head = tid >> 6;
    int lane = tid & 63;

    float val = fbuf[(size_t)n * C_DIM + tid] + h[(size_t)n * C_DIM + tid];

    __shared__ float ws1[HEADS], ws2[HEADS];
    float s1 = val, s2 = val * val;
    #pragma unroll
    for (int off = 32; off > 0; off >>= 1) {
        s1 += __shfl_down(s1, off);
        s2 += __shfl_down(s2, off);
    }
    if (lane == 0) { ws1[head] = s1; ws2[head] = s2; }
    __syncthreads();
    float mean = (ws1[0] + ws1[1] + ws1[2] + ws1[3]) * (1.0f / C_DIM);
    float msq  = (ws2[0] + ws2[1] + ws2[2] + ws2[3]) * (1.0f / C_DIM);
    float var = msq - mean * mean;
    float inv = rsqrtf(var + LN_EPS);
    float o = (val - mean) * inv * ln_g[tid] + ln_b[tid];
    h[(size_t)n * C_DIM + tid] = o;
    hb[(size_t)n * C_DIM + tid] = __float2bfloat16(o);
}

// ---------------------------------------------------------------------------
// Host launch
// ---------------------------------------------------------------------------
extern "C" void kernel_launch(void* const* d_in, const int* in_sizes, int n_in,
                              void* d_out, int out_size, void* d_ws, size_t ws_size,
                              hipStream_t stream)
{
    const float* hf       = (const float*)d_in[0];
    const float* hs       = (const float*)d_in[1];
    const int*   edge     = (const int*)  d_in[2];
    const float* W        = (const float*)d_in[3];
    const float* att_src  = (const float*)d_in[4];
    const float* att_dst  = (const float*)d_in[5];
    const float* gat_b    = (const float*)d_in[6];
    const float* w1       = (const float*)d_in[7];
    const float* b1       = (const float*)d_in[8];
    const float* w2       = (const float*)d_in[9];
    const float* b2       = (const float*)d_in[10];
    const float* ln1g     = (const float*)d_in[11];
    const float* ln1b     = (const float*)d_in[12];
    const float* ln2g     = (const float*)d_in[13];
    const float* ln2b     = (const float*)d_in[14];
    float* out = (float*)d_out;

    const int N = in_sizes[0] / HID;       // 20000
    const int E = in_sizes[2] / 2;         // 320000
    const int* e_src = edge;
    const int* e_dst = edge + E;

    char* p = (char*)d_ws;
    auto alloc = [&](size_t bytes) {
        char* r = p;
        p += (bytes + 255) & ~(size_t)255;
        return (void*)r;
    };
    float*          h      = (float*)alloc((size_t)N * C_DIM * 4);
    __hip_bfloat16* hb     = (__hip_bfloat16*)alloc((size_t)N * C_DIM * 2);
    float*          xh     = (float*)alloc((size_t)N * C_DIM * 4);   // GEMM1 + GEMM3 out
    __hip_bfloat16* midb   = (__hip_bfloat16*)alloc((size_t)N * FF_DIM * 2);
    float*          a_s    = (float*)alloc((size_t)N * HEADS * 4);
    float*          a_d    = (float*)alloc((size_t)N * HEADS * 4);
    float*          selfw  = (float*)alloc((size_t)N * HEADS * 4);
    float*          ebuf   = (float*)alloc((size_t)E * HEADS * 4);   // e-vals -> alpha
    int*            counts = (int*)alloc((size_t)N * 4);
    int*            offs   = (int*)alloc((size_t)(N + 1) * 4);
    int*            cursor = (int*)alloc((size_t)N * 4);
    int*            csr    = (int*)alloc((size_t)E * 4);
    __hip_bfloat16* WT     = (__hip_bfloat16*)alloc((size_t)NLAYERS * C_DIM * C_DIM * 2);
    __hip_bfloat16* w1T    = (__hip_bfloat16*)alloc((size_t)NLAYERS * C_DIM * FF_DIM * 2);
    __hip_bfloat16* w2T    = (__hip_bfloat16*)alloc((size_t)NLAYERS * FF_DIM * C_DIM * 2);

    // h = concat(hf, hs) (+ bf16 shadow)
    {
        int total = N * C_DIM;
        concat_kernel<<<(total + 255) / 256, 256, 0, stream>>>(hf, hs, h, hb, N);
    }
    // Weight transpose+convert (once per call, all layers via blockIdx.z)
    transp_bf16_kernel<<<dim3(C_DIM / 32, C_DIM / 32, NLAYERS), 256, 0, stream>>>(W, WT, C_DIM, C_DIM);
    transp_bf16_kernel<<<dim3(FF_DIM / 32, C_DIM / 32, NLAYERS), 256, 0, stream>>>(w1, w1T, C_DIM, FF_DIM);
    transp_bf16_kernel<<<dim3(C_DIM / 32, FF_DIM / 32, NLAYERS), 256, 0, stream>>>(w2, w2T, FF_DIM, C_DIM);

    // CSR build
    zero_i32_kernel<<<(N + 255) / 256, 256, 0, stream>>>(counts, N);
    hist_kernel<<<(E + 255) / 256, 256, 0, stream>>>(e_dst, counts, E);
    scan_kernel<<<1, 1024, 0, stream>>>(counts, offs, cursor, N);
    fill_kernel<<<(E + 255) / 256, 256, 0, stream>>>(e_src, e_dst, cursor, csr, E);

    const int gm = (N + BM - 1) / BM;   // 157

    for (int l = 0; l < NLAYERS; ++l) {
        const __hip_bfloat16* Wl  = WT  + (size_t)l * C_DIM * C_DIM;
        const __hip_bfloat16* w1l = w1T + (size_t)l * C_DIM * FF_DIM;
        const __hip_bfloat16* w2l = w2T + (size_t)l * FF_DIM * C_DIM;
        const float* asl  = att_src + (size_t)l * C_DIM;
        const float* adl  = att_dst + (size_t)l * C_DIM;
        const float* gbl  = gat_b + (size_t)l * C_DIM;
        const float* b1l  = b1 + (size_t)l * FF_DIM;
        const float* b2l  = b2 + (size_t)l * C_DIM;
        const float* g1l  = ln1g + (size_t)l * C_DIM;
        const float* be1l = ln1b + (size_t)l * C_DIM;
        const float* g2l  = ln2g + (size_t)l * C_DIM;
        const float* be2l = ln2b + (size_t)l * C_DIM;

        // xh = h @ W[l]  (fp32 out)
        gemm_bf16_kernel<<<dim3(gm, C_DIM / BN), 256, 0, stream>>>(
            hb, Wl, nullptr, xh, nullptr, N, C_DIM, C_DIM, 0);
        // attention coefficients
        attn_kernel<<<N, 256, 0, stream>>>(xh, asl, adl, a_s, a_d);
        // per-edge softmax weights
        alpha_kernel<<<(N + 3) / 4, 256, 0, stream>>>(a_s, a_d, csr, offs, ebuf, selfw, N);
        // aggregation + bias + residual + LN1 (h, hb in place)
        agg_kernel<<<N, 256, 0, stream>>>(xh, ebuf, selfw, csr, offs, gbl, g1l, be1l, h, hb);
        // mid = relu(h @ w1 + b1)  (bf16 out)
        gemm_bf16_kernel<<<dim3(gm, FF_DIM / BN), 256, 0, stream>>>(
            hb, w1l, b1l, nullptr, midb, N, FF_DIM, C_DIM, 1);
        // xh = mid @ w2 + b2  (fp32 out)
        gemm_bf16_kernel<<<dim3(gm, C_DIM / BN), 256, 0, stream>>>(
            midb, w2l, b2l, xh, nullptr, N, C_DIM, FF_DIM, 0);
        // h = LN(xh + h)
        ln2_kernel<<<N, 256, 0, stream>>>(xh, g2l, be2l, h, hb);
    }

    {
        int total = N * HID;
        split_kernel<<<(total + 255) / 256, 256, 0, stream>>>(h, out, N);
    }
}

// Round 3
// 1724.607 us; speedup vs baseline: 2.2953x; 1.1936x over previous
//
#include <hip/hip_runtime.h>
#include <hip/hip_bf16.h>
#include <math.h>

// Problem dims (fixed by reference)
#define C_DIM 256      // h width
#define HID 128
#define HEADS 4
#define OC 64          // per-head out channels
#define FF_DIM 512
#define NLAYERS 12

constexpr float LN_EPS = 1e-5f;
constexpr float SLOPE  = 0.2f;

typedef __attribute__((ext_vector_type(4))) float f32x4;
typedef __attribute__((ext_vector_type(8))) short bf16x8_t;
typedef __attribute__((ext_vector_type(4))) int i32x4;

__device__ __forceinline__ float leaky(float x) { return x > 0.f ? x : SLOPE * x; }

// ---------------------------------------------------------------------------
// Small utility kernels
// ---------------------------------------------------------------------------
__global__ void zero_i32_kernel(int* __restrict__ p, int n) {
    int i = blockIdx.x * blockDim.x + threadIdx.x;
    if (i < n) p[i] = 0;
}

__global__ void concat_kernel(const float* __restrict__ hf, const float* __restrict__ hs,
                              float* __restrict__ h, __hip_bfloat16* __restrict__ hb, int Nn) {
    int idx = blockIdx.x * blockDim.x + threadIdx.x;
    int total = Nn * C_DIM;
    if (idx < total) {
        int n = idx >> 8;
        int c = idx & 255;
        float v = (c < HID) ? hf[n * HID + c] : hs[n * HID + (c - HID)];
        h[idx] = v;
        hb[idx] = __float2bfloat16(v);
    }
}

__global__ void split_kernel(const float* __restrict__ h, float* __restrict__ out, int Nn) {
    int idx = blockIdx.x * blockDim.x + threadIdx.x;
    int total = Nn * HID;
    if (idx < total) {
        int n = idx / HID;
        int c = idx - n * HID;
        out[idx]         = h[n * C_DIM + c];
        out[total + idx] = h[n * C_DIM + HID + c];
    }
}

// Transpose + convert weights: in [L][K][N] fp32 -> out [L][N][K] bf16
__global__ void transp_bf16_kernel(const float* __restrict__ in,
                                   __hip_bfloat16* __restrict__ out, int K, int N) {
    __shared__ float t[32][33];
    const float* inl = in + (size_t)blockIdx.z * K * N;
    __hip_bfloat16* outl = out + (size_t)blockIdx.z * K * N;
    int kb = blockIdx.y * 32, nb = blockIdx.x * 32;
    int tx = threadIdx.x & 31, ty = threadIdx.x >> 5; // 32x8
    #pragma unroll
    for (int r = 0; r < 32; r += 8)
        t[ty + r][tx] = inl[(size_t)(kb + ty + r) * N + nb + tx];
    __syncthreads();
    #pragma unroll
    for (int r = 0; r < 32; r += 8)
        outl[(size_t)(nb + ty + r) * K + kb + tx] = __float2bfloat16(t[tx][ty + r]);
}

// ---------------------------------------------------------------------------
// CSR build: histogram of dst, exclusive scan, fill src lists
// ---------------------------------------------------------------------------
__global__ void hist_kernel(const int* __restrict__ dst, int* __restrict__ counts, int E) {
    int e = blockIdx.x * blockDim.x + threadIdx.x;
    if (e < E) atomicAdd(&counts[dst[e]], 1);
}

__global__ void scan_kernel(const int* __restrict__ counts, int* __restrict__ offsets,
                            int* __restrict__ cursor, int n) {
    __shared__ int sdata[1024];
    __shared__ int carry;
    if (threadIdx.x == 0) carry = 0;
    __syncthreads();
    for (int base = 0; base < n; base += 1024) {
        int i = base + (int)threadIdx.x;
        int v = (i < n) ? counts[i] : 0;
        sdata[threadIdx.x] = v;
        __syncthreads();
        for (int off = 1; off < 1024; off <<= 1) {
            int t = (threadIdx.x >= (unsigned)off) ? sdata[threadIdx.x - off] : 0;
            __syncthreads();
            sdata[threadIdx.x] += t;
            __syncthreads();
        }
        int incl = sdata[threadIdx.x];
        int excl = incl - v;
        if (i < n) {
            offsets[i] = carry + excl;
            cursor[i]  = carry + excl;
        }
        __syncthreads();
        if (threadIdx.x == 1023) carry += sdata[1023];
        __syncthreads();
    }
    if (threadIdx.x == 0) offsets[n] = carry;
}

__global__ void fill_kernel(const int* __restrict__ src, const int* __restrict__ dst,
                            int* __restrict__ cursor, int* __restrict__ csr_src, int E) {
    int e = blockIdx.x * blockDim.x + threadIdx.x;
    if (e < E) {
        int d = dst[e];
        int p = atomicAdd(&cursor[d], 1);
        csr_src[p] = src[e];
    }
}

// ---------------------------------------------------------------------------
// bf16 MFMA GEMM: C = op(A[MxK]_bf16 @ (BT[NxK]_bf16)^T + bias)
// 128x128 tile, BK=32, 256 threads (4 waves, 2x2), 4x4 MFMA 16x16x32 per wave.
// A-frag: A[m=lane&15][k=(lane>>4)*8+j]; B-frag: B[k=(lane>>4)*8+j][n=lane&15]
// C/D:    col=lane&15, row=(lane>>4)*4+reg  [verified m89/m91]
// Optional fused attention-coefficient epilogue (aS/aD non-null): each wave's
// 64 columns are exactly one head, so a_s/a_d row-dots reduce fully in-wave
// (shfl_xor over 16-lane quads) — deterministic direct stores, no atomics.
// ---------------------------------------------------------------------------
#define BM 128
#define BN 128
#define BK 32
#define LSTR 40   // LDS row stride (shorts): 80B, 16B-aligned; 2-way alias = free

__global__ __launch_bounds__(256) void gemm_bf16_kernel(
    const __hip_bfloat16* __restrict__ A,   // [M x K] bf16 row-major
    const __hip_bfloat16* __restrict__ BT,  // [N x K] bf16 row-major (B^T)
    const float* __restrict__ bias,         // [N] or null
    float* __restrict__ Cf,                 // fp32 out or null
    __hip_bfloat16* __restrict__ Cb,        // bf16 out or null
    const float* __restrict__ attS,         // [N] att_src (layer slice) or null
    const float* __restrict__ attD,         // [N] att_dst or null
    float* __restrict__ aS,                 // [M x HEADS] out or null
    float* __restrict__ aD,
    int M, int N, int K, int relu)
{
    __shared__ short As[BM * LSTR];
    __shared__ short Bs[BN * LSTR];
    const int tid = threadIdx.x;
    const int wave = tid >> 6, lane = tid & 63;
    const int lr = lane & 15, lq = lane >> 4;
    const int wm = (wave >> 1) * 64, wn = (wave & 1) * 64;
    const int row0 = blockIdx.x * BM, col0 = blockIdx.y * BN;

    const int r0 = tid >> 2;              // 0..63
    const int kc0 = (tid & 3) * 8;        // 0,8,16,24

    f32x4 acc[4][4] = {};

    for (int k0 = 0; k0 < K; k0 += BK) {
        int gr = row0 + r0;
        i32x4 va = {};
        if (gr < M) va = *(const i32x4*)&A[(size_t)gr * K + k0 + kc0];
        *(i32x4*)&As[r0 * LSTR + kc0] = va;
        gr = row0 + r0 + 64;
        i32x4 va2 = {};
        if (gr < M) va2 = *(const i32x4*)&A[(size_t)gr * K + k0 + kc0];
        *(i32x4*)&As[(r0 + 64) * LSTR + kc0] = va2;
        i32x4 vb = *(const i32x4*)&BT[(size_t)(col0 + r0) * K + k0 + kc0];
        *(i32x4*)&Bs[r0 * LSTR + kc0] = vb;
        i32x4 vb2 = *(const i32x4*)&BT[(size_t)(col0 + r0 + 64) * K + k0 + kc0];
        *(i32x4*)&Bs[(r0 + 64) * LSTR + kc0] = vb2;
        __syncthreads();

        bf16x8_t afrag[4], bfrag[4];
        #pragma unroll
        for (int t = 0; t < 4; ++t) {
            afrag[t] = *(const bf16x8_t*)&As[(wm + t * 16 + lr) * LSTR + lq * 8];
            bfrag[t] = *(const bf16x8_t*)&Bs[(wn + t * 16 + lr) * LSTR + lq * 8];
        }
        #pragma unroll
        for (int mt = 0; mt < 4; ++mt)
            #pragma unroll
            for (int nt = 0; nt < 4; ++nt)
                acc[mt][nt] = __builtin_amdgcn_mfma_f32_16x16x32_bf16(
                    afrag[mt], bfrag[nt], acc[mt][nt], 0, 0, 0);
        __syncthreads();
    }

    float bv[4];
    #pragma unroll
    for (int nt = 0; nt < 4; ++nt)
        bv[nt] = bias ? bias[col0 + wn + nt * 16 + lr] : 0.f;

    #pragma unroll
    for (int mt = 0; mt < 4; ++mt) {
        #pragma unroll
        for (int r = 0; r < 4; ++r) {
            int grow = row0 + wm + mt * 16 + lq * 4 + r;
            if (grow >= M) continue;
            #pragma unroll
            for (int nt = 0; nt < 4; ++nt) {
                float v = acc[mt][nt][r] + bv[nt];
                if (relu) v = fmaxf(v, 0.f);
                int gcol = col0 + wn + nt * 16 + lr;
                if (Cf) Cf[(size_t)grow * N + gcol] = v;
                if (Cb) Cb[(size_t)grow * N + gcol] = __float2bfloat16(v);
            }
        }
    }

    // Fused attention-coefficient epilogue (gemm1 only)
    if (aS) {
        const int head = (col0 + wn) >> 6;   // this wave's 64 cols = one head
        float atS[4], atD[4];
        #pragma unroll
        for (int nt = 0; nt < 4; ++nt) {
            int c = col0 + wn + nt * 16 + lr;
            atS[nt] = attS[c];
            atD[nt] = attD[c];
        }
        #pragma unroll
        for (int mt = 0; mt < 4; ++mt) {
            #pragma unroll
            for (int r = 0; r < 4; ++r) {
                float vs = 0.f, vd = 0.f;
                #pragma unroll
                for (int nt = 0; nt < 4; ++nt) {
                    float a = acc[mt][nt][r];
                    vs += a * atS[nt];
                    vd += a * atD[nt];
                }
                #pragma unroll
                for (int off = 1; off < 16; off <<= 1) {
                    vs += __shfl_xor(vs, off);
                    vd += __shfl_xor(vd, off);
                }
                if (lr == 0) {
                    int row = row0 + wm + mt * 16 + lq * 4 + r;
                    if (row < M) {
                        aS[row * HEADS + head] = vs;
                        aD[row * HEADS + head] = vd;
                    }
                }
            }
        }
    }
}

// ---------------------------------------------------------------------------
// Fused GAT: segment-softmax (unnormalized exp — logits bounded, no max
// needed) + weighted bf16 gather + bias + residual + LN. Block (256) per node.
// Per-64-edge chunk: phase A computes exp-weights into LDS (lanes parallel,
// one thread per (edge,head)); phase B gathers with broadcast LDS reads.
// ---------------------------------------------------------------------------
__global__ __launch_bounds__(256) void agg_kernel(
    const __hip_bfloat16* __restrict__ xhb, const float* __restrict__ a_s,
    const float* __restrict__ a_d, const int* __restrict__ csr,
    const int* __restrict__ offs, const float* __restrict__ gat_b,
    const float* __restrict__ ln_g, const float* __restrict__ ln_b,
    float* __restrict__ h, __hip_bfloat16* __restrict__ hb)
{
    int n = blockIdx.x;
    int tid = threadIdx.x;
    int head = tid >> 6;
    int lane = tid & 63;

    __shared__ float wbuf[64 * HEADS];

    float ad = a_d[n * HEADS + head];
    float wself = __expf(leaky(a_s[n * HEADS + head] + ad));
    float acc0 = wself * __bfloat162float(xhb[(size_t)n * C_DIM + tid]);
    float acc1 = 0.f, acc2 = 0.f, acc3 = 0.f;
    float z = wself;

    int beg = offs[n], end = offs[n + 1];
    for (int base = beg; base < end; base += 64) {
        int cnt = min(64, end - base);
        // phase A: per-edge exp-weights (thread (j,head) -> wbuf[j][head])
        if (lane < cnt) {
            int s = csr[base + lane];
            wbuf[lane * HEADS + head] = __expf(leaky(a_s[s * HEADS + head] + ad));
        }
        __syncthreads();
        // phase B: weighted gather
        int i = 0;
        for (; i + 4 <= cnt; i += 4) {
            int s0 = csr[base + i], s1 = csr[base + i + 1];
            int s2 = csr[base + i + 2], s3 = csr[base + i + 3];
            float w0 = wbuf[(i + 0) * HEADS + head];
            float w1 = wbuf[(i + 1) * HEADS + head];
            float w2 = wbuf[(i + 2) * HEADS + head];
            float w3 = wbuf[(i + 3) * HEADS + head];
            acc0 += w0 * __bfloat162float(xhb[(size_t)s0 * C_DIM + tid]);
            acc1 += w1 * __bfloat162float(xhb[(size_t)s1 * C_DIM + tid]);
            acc2 += w2 * __bfloat162float(xhb[(size_t)s2 * C_DIM + tid]);
            acc3 += w3 * __bfloat162float(xhb[(size_t)s3 * C_DIM + tid]);
            z += (w0 + w1) + (w2 + w3);
        }
        for (; i < cnt; ++i) {
            int s0 = csr[base + i];
            float w0 = wbuf[i * HEADS + head];
            acc0 += w0 * __bfloat162float(xhb[(size_t)s0 * C_DIM + tid]);
            z += w0;
        }
        __syncthreads();
    }

    float val = ((acc0 + acc1) + (acc2 + acc3)) / z + gat_b[tid] + h[(size_t)n * C_DIM + tid];

    __shared__ float ws1[HEADS], ws2[HEADS];
    float s1 = val, s2 = val * val;
    #pragma unroll
    for (int off = 32; off > 0; off >>= 1) {
        s1 += __shfl_down(s1, off);
        s2 += __shfl_down(s2, off);
    }
    if (lane == 0) { ws1[head] = s1; ws2[head] = s2; }
    __syncthreads();
    float mean = (ws1[0] + ws1[1] + ws1[2] + ws1[3]) * (1.0f / C_DIM);
    float msq  = (ws2[0] + ws2[1] + ws2[2] + ws2[3]) * (1.0f / C_DIM);
    float var = msq - mean * mean;
    float inv = rsqrtf(var + LN_EPS);
    float o = (val - mean) * inv * ln_g[tid] + ln_b[tid];
    h[(size_t)n * C_DIM + tid] = o;
    hb[(size_t)n * C_DIM + tid] = __float2bfloat16(o);
}

// ---------------------------------------------------------------------------
// ln2: h = LN(fbuf + h); writes fp32 h and bf16 hb
// ---------------------------------------------------------------------------
__global__ __launch_bounds__(256) void ln2_kernel(
    const float* __restrict__ fbuf, const float* __restrict__ ln_g,
    const float* __restrict__ ln_b, float* __restrict__ h,
    __hip_bfloat16* __restrict__ hb)
{
    int n = blockIdx.x;
    int tid = threadIdx.x;
    int head = tid >> 6;
    int lane = tid & 63;

    float val = fbuf[(size_t)n * C_DIM + tid] + h[(size_t)n * C_DIM + tid];

    __shared__ float ws1[HEADS], ws2[HEADS];
    float s1 = val, s2 = val * val;
    #pragma unroll
    for (int off = 32; off > 0; off >>= 1) {
        s1 += __shfl_down(s1, off);
        s2 += __shfl_down(s2, off);
    }
    if (lane == 0) { ws1[head] = s1; ws2[head] = s2; }
    __syncthreads();
    float mean = (ws1[0] + ws1[1] + ws1[2] + ws1[3]) * (1.0f / C_DIM);
    float msq  = (ws2[0] + ws2[1] + ws2[2] + ws2[3]) * (1.0f / C_DIM);
    float var = msq - mean * mean;
    float inv = rsqrtf(var + LN_EPS);
    float o = (val - mean) * inv * ln_g[tid] + ln_b[tid];
    h[(size_t)n * C_DIM + tid] = o;
    hb[(size_t)n * C_DIM + tid] = __float2bfloat16(o);
}

// ---------------------------------------------------------------------------
// Host launch
// ---------------------------------------------------------------------------
extern "C" void kernel_launch(void* const* d_in, const int* in_sizes, int n_in,
                              void* d_out, int out_size, void* d_ws, size_t ws_size,
                              hipStream_t stream)
{
    const float* hf       = (const float*)d_in[0];
    const float* hs       = (const float*)d_in[1];
    const int*   edge     = (const int*)  d_in[2];
    const float* W        = (const float*)d_in[3];
    const float* att_src  = (const float*)d_in[4];
    const float* att_dst  = (const float*)d_in[5];
    const float* gat_b    = (const float*)d_in[6];
    const float* w1       = (const float*)d_in[7];
    const float* b1       = (const float*)d_in[8];
    const float* w2       = (const float*)d_in[9];
    const float* b2       = (const float*)d_in[10];
    const float* ln1g     = (const float*)d_in[11];
    const float* ln1b     = (const float*)d_in[12];
    const float* ln2g     = (const float*)d_in[13];
    const float* ln2b     = (const float*)d_in[14];
    float* out = (float*)d_out;

    const int N = in_sizes[0] / HID;       // 20000
    const int E = in_sizes[2] / 2;         // 320000
    const int* e_src = edge;
    const int* e_dst = edge + E;

    char* p = (char*)d_ws;
    auto alloc = [&](size_t bytes) {
        char* r = p;
        p += (bytes + 255) & ~(size_t)255;
        return (void*)r;
    };
    float*          h      = (float*)alloc((size_t)N * C_DIM * 4);
    __hip_bfloat16* hb     = (__hip_bfloat16*)alloc((size_t)N * C_DIM * 2);
    __hip_bfloat16* xhb    = (__hip_bfloat16*)alloc((size_t)N * C_DIM * 2);  // gemm1 out
    float*          fbuf   = (float*)alloc((size_t)N * C_DIM * 4);           // gemm3 out
    __hip_bfloat16* midb   = (__hip_bfloat16*)alloc((size_t)N * FF_DIM * 2);
    float*          a_s    = (float*)alloc((size_t)N * HEADS * 4);
    float*          a_d    = (float*)alloc((size_t)N * HEADS * 4);
    int*            counts = (int*)alloc((size_t)N * 4);
    int*            offs   = (int*)alloc((size_t)(N + 1) * 4);
    int*            cursor = (int*)alloc((size_t)N * 4);
    int*            csr    = (int*)alloc((size_t)E * 4);
    __hip_bfloat16* WT     = (__hip_bfloat16*)alloc((size_t)NLAYERS * C_DIM * C_DIM * 2);
    __hip_bfloat16* w1T    = (__hip_bfloat16*)alloc((size_t)NLAYERS * C_DIM * FF_DIM * 2);
    __hip_bfloat16* w2T    = (__hip_bfloat16*)alloc((size_t)NLAYERS * FF_DIM * C_DIM * 2);

    // h = concat(hf, hs) (+ bf16 shadow)
    {
        int total = N * C_DIM;
        concat_kernel<<<(total + 255) / 256, 256, 0, stream>>>(hf, hs, h, hb, N);
    }
    // Weight transpose+convert (once per call, all layers via blockIdx.z)
    transp_bf16_kernel<<<dim3(C_DIM / 32, C_DIM / 32, NLAYERS), 256, 0, stream>>>(W, WT, C_DIM, C_DIM);
    transp_bf16_kernel<<<dim3(FF_DIM / 32, C_DIM / 32, NLAYERS), 256, 0, stream>>>(w1, w1T, C_DIM, FF_DIM);
    transp_bf16_kernel<<<dim3(C_DIM / 32, FF_DIM / 32, NLAYERS), 256, 0, stream>>>(w2, w2T, FF_DIM, C_DIM);

    // CSR build
    zero_i32_kernel<<<(N + 255) / 256, 256, 0, stream>>>(counts, N);
    hist_kernel<<<(E + 255) / 256, 256, 0, stream>>>(e_dst, counts, E);
    scan_kernel<<<1, 1024, 0, stream>>>(counts, offs, cursor, N);
    fill_kernel<<<(E + 255) / 256, 256, 0, stream>>>(e_src, e_dst, cursor, csr, E);

    const int gm = (N + BM - 1) / BM;   // 157

    for (int l = 0; l < NLAYERS; ++l) {
        const __hip_bfloat16* Wl  = WT  + (size_t)l * C_DIM * C_DIM;
        const __hip_bfloat16* w1l = w1T + (size_t)l * C_DIM * FF_DIM;
        const __hip_bfloat16* w2l = w2T + (size_t)l * FF_DIM * C_DIM;
        const float* asl  = att_src + (size_t)l * C_DIM;
        const float* adl  = att_dst + (size_t)l * C_DIM;
        const float* gbl  = gat_b + (size_t)l * C_DIM;
        const float* b1l  = b1 + (size_t)l * FF_DIM;
        const float* b2l  = b2 + (size_t)l * C_DIM;
        const float* g1l  = ln1g + (size_t)l * C_DIM;
        const float* be1l = ln1b + (size_t)l * C_DIM;
        const float* g2l  = ln2g + (size_t)l * C_DIM;
        const float* be2l = ln2b + (size_t)l * C_DIM;

        // xhb = h @ W[l] (bf16 out) + fused a_s/a_d epilogue
        gemm_bf16_kernel<<<dim3(gm, C_DIM / BN), 256, 0, stream>>>(
            hb, Wl, nullptr, nullptr, xhb, asl, adl, a_s, a_d, N, C_DIM, C_DIM, 0);
        // fused softmax + aggregation + bias + residual + LN1 (h, hb in place)
        agg_kernel<<<N, 256, 0, stream>>>(xhb, a_s, a_d, csr, offs, gbl, g1l, be1l, h, hb);
        // mid = relu(h @ w1 + b1)  (bf16 out)
        gemm_bf16_kernel<<<dim3(gm, FF_DIM / BN), 256, 0, stream>>>(
            hb, w1l, b1l, nullptr, midb, nullptr, nullptr, nullptr, nullptr,
            N, FF_DIM, C_DIM, 1);
        // fbuf = mid @ w2 + b2  (fp32 out)
        gemm_bf16_kernel<<<dim3(gm, C_DIM / BN), 256, 0, stream>>>(
            midb, w2l, b2l, fbuf, nullptr, nullptr, nullptr, nullptr, nullptr,
            N, C_DIM, FF_DIM, 0);
        // h = LN(fbuf + h)
        ln2_kernel<<<N, 256, 0, stream>>>(fbuf, g2l, be2l, h, hb);
    }

    {
        int total = N * HID;
        split_kernel<<<(total + 255) / 256, 256, 0, stream>>>(h, out, N);
    }
}

// Round 4
// 1483.753 us; speedup vs baseline: 2.6679x; 1.1623x over previous
//
#include <hip/hip_runtime.h>
#include <hip/hip_bf16.h>
#include <math.h>

// Problem dims (fixed by reference)
#define C_DIM 256      // h width
#define HID 128
#define HEADS 4
#define OC 64          // per-head out channels
#define FF_DIM 512
#define NLAYERS 12

constexpr float LN_EPS = 1e-5f;
constexpr float SLOPE  = 0.2f;

typedef __attribute__((ext_vector_type(4))) float f32x4;
typedef __attribute__((ext_vector_type(8))) short bf16x8_t;
typedef __attribute__((ext_vector_type(4))) int i32x4;

__device__ __forceinline__ float leaky(float x) { return x > 0.f ? x : SLOPE * x; }

__device__ __forceinline__ float bf2f(unsigned short u) {
    union { unsigned i; float f; } v; v.i = ((unsigned)u) << 16; return v.f;
}

// ---------------------------------------------------------------------------
// Small utility kernels
// ---------------------------------------------------------------------------
__global__ void zero_i32_kernel(int* __restrict__ p, int n) {
    int i = blockIdx.x * blockDim.x + threadIdx.x;
    if (i < n) p[i] = 0;
}

__global__ void concat_kernel(const float* __restrict__ hf, const float* __restrict__ hs,
                              float* __restrict__ h, __hip_bfloat16* __restrict__ hb, int Nn) {
    int idx = blockIdx.x * blockDim.x + threadIdx.x;
    int total = Nn * C_DIM;
    if (idx < total) {
        int n = idx >> 8;
        int c = idx & 255;
        float v = (c < HID) ? hf[n * HID + c] : hs[n * HID + (c - HID)];
        h[idx] = v;
        hb[idx] = __float2bfloat16(v);
    }
}

// Transpose + convert weights: in [L][K][N] fp32 -> out [L][N][K] bf16
__global__ void transp_bf16_kernel(const float* __restrict__ in,
                                   __hip_bfloat16* __restrict__ out, int K, int N) {
    __shared__ float t[32][33];
    const float* inl = in + (size_t)blockIdx.z * K * N;
    __hip_bfloat16* outl = out + (size_t)blockIdx.z * K * N;
    int kb = blockIdx.y * 32, nb = blockIdx.x * 32;
    int tx = threadIdx.x & 31, ty = threadIdx.x >> 5; // 32x8
    #pragma unroll
    for (int r = 0; r < 32; r += 8)
        t[ty + r][tx] = inl[(size_t)(kb + ty + r) * N + nb + tx];
    __syncthreads();
    #pragma unroll
    for (int r = 0; r < 32; r += 8)
        outl[(size_t)(nb + ty + r) * K + kb + tx] = __float2bfloat16(t[tx][ty + r]);
}

// ---------------------------------------------------------------------------
// CSR build: histogram of dst, exclusive scan, fill src+dst lists
// ---------------------------------------------------------------------------
__global__ void hist_kernel(const int* __restrict__ dst, int* __restrict__ counts, int E) {
    int e = blockIdx.x * blockDim.x + threadIdx.x;
    if (e < E) atomicAdd(&counts[dst[e]], 1);
}

__global__ void scan_kernel(const int* __restrict__ counts, int* __restrict__ offsets,
                            int* __restrict__ cursor, int n) {
    __shared__ int sdata[1024];
    __shared__ int carry;
    if (threadIdx.x == 0) carry = 0;
    __syncthreads();
    for (int base = 0; base < n; base += 1024) {
        int i = base + (int)threadIdx.x;
        int v = (i < n) ? counts[i] : 0;
        sdata[threadIdx.x] = v;
        __syncthreads();
        for (int off = 1; off < 1024; off <<= 1) {
            int t = (threadIdx.x >= (unsigned)off) ? sdata[threadIdx.x - off] : 0;
            __syncthreads();
            sdata[threadIdx.x] += t;
            __syncthreads();
        }
        int incl = sdata[threadIdx.x];
        int excl = incl - v;
        if (i < n) {
            offsets[i] = carry + excl;
            cursor[i]  = carry + excl;
        }
        __syncthreads();
        if (threadIdx.x == 1023) carry += sdata[1023];
        __syncthreads();
    }
    if (threadIdx.x == 0) offsets[n] = carry;
}

__global__ void fill_kernel(const int* __restrict__ src, const int* __restrict__ dst,
                            int* __restrict__ cursor, int* __restrict__ csr_src,
                            int* __restrict__ csr_dst, int E) {
    int e = blockIdx.x * blockDim.x + threadIdx.x;
    if (e < E) {
        int d = dst[e];
        int p = atomicAdd(&cursor[d], 1);
        csr_src[p] = src[e];
        csr_dst[p] = d;
    }
}

// ---------------------------------------------------------------------------
// Per-edge exp weights (no max-subtraction: logits bounded ~|3|, validated R2).
// One thread per CSR slot, all 4 heads.
// ---------------------------------------------------------------------------
__global__ void wexp_kernel(const int* __restrict__ csr, const int* __restrict__ csr_dst,
                            const float* __restrict__ a_s, const float* __restrict__ a_d,
                            float* __restrict__ wexp, int E) {
    int i = blockIdx.x * blockDim.x + threadIdx.x;
    if (i >= E) return;
    int s = csr[i], d = csr_dst[i];
    float4 av = *(const float4*)&a_s[(size_t)s * 4];
    float4 dv = *(const float4*)&a_d[(size_t)d * 4];
    float4 w;
    w.x = __expf(leaky(av.x + dv.x));
    w.y = __expf(leaky(av.y + dv.y));
    w.z = __expf(leaky(av.z + dv.z));
    w.w = __expf(leaky(av.w + dv.w));
    *(float4*)&wexp[(size_t)i * 4] = w;
}

// ---------------------------------------------------------------------------
// bf16 MFMA GEMM: C = op(A[MxK]_bf16 @ (BT[NxK]_bf16)^T + bias)
// 128x128 tile, BK=32, 256 threads (4 waves, 2x2), 4x4 MFMA 16x16x32 per wave.
// C/D: col=lane&15, row=(lane>>4)*4+reg  [verified m89/m91]
// Optional fused attention-coefficient epilogue (aS non-null).
// ---------------------------------------------------------------------------
#define BM 128
#define BN 128
#define BK 32
#define LSTR 40   // LDS row stride (shorts): 80B, 16B-aligned; 2-way alias = free

__global__ __launch_bounds__(256) void gemm_bf16_kernel(
    const __hip_bfloat16* __restrict__ A,   // [M x K] bf16 row-major
    const __hip_bfloat16* __restrict__ BT,  // [N x K] bf16 row-major (B^T)
    const float* __restrict__ bias,         // [N] or null
    float* __restrict__ Cf,                 // fp32 out or null
    __hip_bfloat16* __restrict__ Cb,        // bf16 out or null
    const float* __restrict__ attS,         // [N] att_src (layer slice) or null
    const float* __restrict__ attD,
    float* __restrict__ aS,                 // [M x HEADS] out or null
    float* __restrict__ aD,
    int M, int N, int K, int relu)
{
    __shared__ short As[BM * LSTR];
    __shared__ short Bs[BN * LSTR];
    const int tid = threadIdx.x;
    const int wave = tid >> 6, lane = tid & 63;
    const int lr = lane & 15, lq = lane >> 4;
    const int wm = (wave >> 1) * 64, wn = (wave & 1) * 64;
    const int row0 = blockIdx.x * BM, col0 = blockIdx.y * BN;

    const int r0 = tid >> 2;              // 0..63
    const int kc0 = (tid & 3) * 8;        // 0,8,16,24

    f32x4 acc[4][4] = {};

    for (int k0 = 0; k0 < K; k0 += BK) {
        int gr = row0 + r0;
        i32x4 va = {};
        if (gr < M) va = *(const i32x4*)&A[(size_t)gr * K + k0 + kc0];
        *(i32x4*)&As[r0 * LSTR + kc0] = va;
        gr = row0 + r0 + 64;
        i32x4 va2 = {};
        if (gr < M) va2 = *(const i32x4*)&A[(size_t)gr * K + k0 + kc0];
        *(i32x4*)&As[(r0 + 64) * LSTR + kc0] = va2;
        i32x4 vb = *(const i32x4*)&BT[(size_t)(col0 + r0) * K + k0 + kc0];
        *(i32x4*)&Bs[r0 * LSTR + kc0] = vb;
        i32x4 vb2 = *(const i32x4*)&BT[(size_t)(col0 + r0 + 64) * K + k0 + kc0];
        *(i32x4*)&Bs[(r0 + 64) * LSTR + kc0] = vb2;
        __syncthreads();

        bf16x8_t afrag[4], bfrag[4];
        #pragma unroll
        for (int t = 0; t < 4; ++t) {
            afrag[t] = *(const bf16x8_t*)&As[(wm + t * 16 + lr) * LSTR + lq * 8];
            bfrag[t] = *(const bf16x8_t*)&Bs[(wn + t * 16 + lr) * LSTR + lq * 8];
        }
        #pragma unroll
        for (int mt = 0; mt < 4; ++mt)
            #pragma unroll
            for (int nt = 0; nt < 4; ++nt)
                acc[mt][nt] = __builtin_amdgcn_mfma_f32_16x16x32_bf16(
                    afrag[mt], bfrag[nt], acc[mt][nt], 0, 0, 0);
        __syncthreads();
    }

    float bv[4];
    #pragma unroll
    for (int nt = 0; nt < 4; ++nt)
        bv[nt] = bias ? bias[col0 + wn + nt * 16 + lr] : 0.f;

    #pragma unroll
    for (int mt = 0; mt < 4; ++mt) {
        #pragma unroll
        for (int r = 0; r < 4; ++r) {
            int grow = row0 + wm + mt * 16 + lq * 4 + r;
            if (grow >= M) continue;
            #pragma unroll
            for (int nt = 0; nt < 4; ++nt) {
                float v = acc[mt][nt][r] + bv[nt];
                if (relu) v = fmaxf(v, 0.f);
                int gcol = col0 + wn + nt * 16 + lr;
                if (Cf) Cf[(size_t)grow * N + gcol] = v;
                if (Cb) Cb[(size_t)grow * N + gcol] = __float2bfloat16(v);
            }
        }
    }

    // Fused attention-coefficient epilogue (gemm1 only)
    if (aS) {
        const int head = (col0 + wn) >> 6;   // this wave's 64 cols = one head
        float atS[4], atD[4];
        #pragma unroll
        for (int nt = 0; nt < 4; ++nt) {
            int c = col0 + wn + nt * 16 + lr;
            atS[nt] = attS[c];
            atD[nt] = attD[c];
        }
        #pragma unroll
        for (int mt = 0; mt < 4; ++mt) {
            #pragma unroll
            for (int r = 0; r < 4; ++r) {
                float vs = 0.f, vd = 0.f;
                #pragma unroll
                for (int nt = 0; nt < 4; ++nt) {
                    float a = acc[mt][nt][r];
                    vs += a * atS[nt];
                    vd += a * atD[nt];
                }
                #pragma unroll
                for (int off = 1; off < 16; off <<= 1) {
                    vs += __shfl_xor(vs, off);
                    vd += __shfl_xor(vd, off);
                }
                if (lr == 0) {
                    int row = row0 + wm + mt * 16 + lq * 4 + r;
                    if (row < M) {
                        aS[row * HEADS + head] = vs;
                        aD[row * HEADS + head] = vd;
                    }
                }
            }
        }
    }
}

// ---------------------------------------------------------------------------
// Fused GAT aggregation + bias + residual + LN1.
// One WAVE per node (4 nodes / 256-block); lane owns 4 channels (8B gathers).
// head = lane>>4 (channels lane*4..lane*4+3 all in head (lane*4)/64).
// No LDS, no __syncthreads; LN via 64-lane butterfly.
// ---------------------------------------------------------------------------
__global__ __launch_bounds__(256) void agg_kernel(
    const __hip_bfloat16* __restrict__ xhb, const float* __restrict__ a_s,
    const float* __restrict__ a_d, const int* __restrict__ csr,
    const int* __restrict__ offs, const float* __restrict__ wexp,
    const float* __restrict__ gat_b, const float* __restrict__ ln_g,
    const float* __restrict__ ln_b, float* __restrict__ h,
    __hip_bfloat16* __restrict__ hb, int Nn)
{
    const int lane = threadIdx.x & 63;
    const int n = blockIdx.x * 4 + (threadIdx.x >> 6);
    if (n >= Nn) return;
    const int head = lane >> 4;
    const int c0 = lane * 4;
    const unsigned short* x = (const unsigned short*)xhb;

    // residual (issue early)
    float4 res = *(const float4*)&h[(size_t)n * C_DIM + c0];

    float wself = __expf(leaky(a_s[n * 4 + head] + a_d[n * 4 + head]));
    ushort4 xs = *(const ushort4*)&x[(size_t)n * C_DIM + c0];
    float acc0[4], acc1[4] = {}, acc2[4] = {}, acc3[4] = {};
    acc0[0] = wself * bf2f(xs.x);
    acc0[1] = wself * bf2f(xs.y);
    acc0[2] = wself * bf2f(xs.z);
    acc0[3] = wself * bf2f(xs.w);
    float z = wself;

    const int beg = offs[n], end = offs[n + 1];
    int i = beg;
    for (; i + 4 <= end; i += 4) {
        int s0 = csr[i], s1 = csr[i + 1], s2 = csr[i + 2], s3 = csr[i + 3];
        float w0 = wexp[(size_t)(i + 0) * 4 + head];
        float w1 = wexp[(size_t)(i + 1) * 4 + head];
        float w2 = wexp[(size_t)(i + 2) * 4 + head];
        float w3 = wexp[(size_t)(i + 3) * 4 + head];
        ushort4 x0 = *(const ushort4*)&x[(size_t)s0 * C_DIM + c0];
        ushort4 x1 = *(const ushort4*)&x[(size_t)s1 * C_DIM + c0];
        ushort4 x2 = *(const ushort4*)&x[(size_t)s2 * C_DIM + c0];
        ushort4 x3 = *(const ushort4*)&x[(size_t)s3 * C_DIM + c0];
        acc0[0] += w0 * bf2f(x0.x); acc0[1] += w0 * bf2f(x0.y);
        acc0[2] += w0 * bf2f(x0.z); acc0[3] += w0 * bf2f(x0.w);
        acc1[0] += w1 * bf2f(x1.x); acc1[1] += w1 * bf2f(x1.y);
        acc1[2] += w1 * bf2f(x1.z); acc1[3] += w1 * bf2f(x1.w);
        acc2[0] += w2 * bf2f(x2.x); acc2[1] += w2 * bf2f(x2.y);
        acc2[2] += w2 * bf2f(x2.z); acc2[3] += w2 * bf2f(x2.w);
        acc3[0] += w3 * bf2f(x3.x); acc3[1] += w3 * bf2f(x3.y);
        acc3[2] += w3 * bf2f(x3.z); acc3[3] += w3 * bf2f(x3.w);
        z += (w0 + w1) + (w2 + w3);
    }
    for (; i < end; ++i) {
        int s0 = csr[i];
        float w0 = wexp[(size_t)i * 4 + head];
        ushort4 x0 = *(const ushort4*)&x[(size_t)s0 * C_DIM + c0];
        acc0[0] += w0 * bf2f(x0.x); acc0[1] += w0 * bf2f(x0.y);
        acc0[2] += w0 * bf2f(x0.z); acc0[3] += w0 * bf2f(x0.w);
        z += w0;
    }

    float4 gb = *(const float4*)&gat_b[c0];
    float rz = 1.0f / z;
    float val[4];
    val[0] = (acc0[0] + acc1[0] + acc2[0] + acc3[0]) * rz + gb.x + res.x;
    val[1] = (acc0[1] + acc1[1] + acc2[1] + acc3[1]) * rz + gb.y + res.y;
    val[2] = (acc0[2] + acc1[2] + acc2[2] + acc3[2]) * rz + gb.z + res.z;
    val[3] = (acc0[3] + acc1[3] + acc2[3] + acc3[3]) * rz + gb.w + res.w;

    float s1 = (val[0] + val[1]) + (val[2] + val[3]);
    float s2 = (val[0] * val[0] + val[1] * val[1]) + (val[2] * val[2] + val[3] * val[3]);
    #pragma unroll
    for (int off = 1; off < 64; off <<= 1) {
        s1 += __shfl_xor(s1, off);
        s2 += __shfl_xor(s2, off);
    }
    float mean = s1 * (1.0f / C_DIM);
    float inv = rsqrtf(s2 * (1.0f / C_DIM) - mean * mean + LN_EPS);
    float4 g = *(const float4*)&ln_g[c0];
    float4 bb = *(const float4*)&ln_b[c0];
    float4 o;
    o.x = (val[0] - mean) * inv * g.x + bb.x;
    o.y = (val[1] - mean) * inv * g.y + bb.y;
    o.z = (val[2] - mean) * inv * g.z + bb.z;
    o.w = (val[3] - mean) * inv * g.w + bb.w;
    *(float4*)&h[(size_t)n * C_DIM + c0] = o;
    ushort4 ob;
    ob.x = (unsigned short)(__bfloat16_as_ushort(__float2bfloat16(o.x)));
    ob.y = (unsigned short)(__bfloat16_as_ushort(__float2bfloat16(o.y)));
    ob.z = (unsigned short)(__bfloat16_as_ushort(__float2bfloat16(o.z)));
    ob.w = (unsigned short)(__bfloat16_as_ushort(__float2bfloat16(o.w)));
    *(ushort4*)&((unsigned short*)hb)[(size_t)n * C_DIM + c0] = ob;
}

// ---------------------------------------------------------------------------
// ln2: val = bf2f(fb) + h; LN; writes h+hb, or (final layer) split fp32 out.
// One wave per node, no LDS/barriers.
// ---------------------------------------------------------------------------
__global__ __launch_bounds__(256) void ln2_kernel(
    const __hip_bfloat16* __restrict__ fb, const float* __restrict__ ln_g,
    const float* __restrict__ ln_b, float* __restrict__ h,
    __hip_bfloat16* __restrict__ hb, float* __restrict__ out_split, int Nn)
{
    const int lane = threadIdx.x & 63;
    const int n = blockIdx.x * 4 + (threadIdx.x >> 6);
    if (n >= Nn) return;
    const int c0 = lane * 4;
    const unsigned short* f = (const unsigned short*)fb;

    float4 res = *(const float4*)&h[(size_t)n * C_DIM + c0];
    ushort4 fv = *(const ushort4*)&f[(size_t)n * C_DIM + c0];
    float val[4];
    val[0] = bf2f(fv.x) + res.x;
    val[1] = bf2f(fv.y) + res.y;
    val[2] = bf2f(fv.z) + res.z;
    val[3] = bf2f(fv.w) + res.w;

    float s1 = (val[0] + val[1]) + (val[2] + val[3]);
    float s2 = (val[0] * val[0] + val[1] * val[1]) + (val[2] * val[2] + val[3] * val[3]);
    #pragma unroll
    for (int off = 1; off < 64; off <<= 1) {
        s1 += __shfl_xor(s1, off);
        s2 += __shfl_xor(s2, off);
    }
    float mean = s1 * (1.0f / C_DIM);
    float inv = rsqrtf(s2 * (1.0f / C_DIM) - mean * mean + LN_EPS);
    float4 g = *(const float4*)&ln_g[c0];
    float4 bb = *(const float4*)&ln_b[c0];
    float4 o;
    o.x = (val[0] - mean) * inv * g.x + bb.x;
    o.y = (val[1] - mean) * inv * g.y + bb.y;
    o.z = (val[2] - mean) * inv * g.z + bb.z;
    o.w = (val[3] - mean) * inv * g.w + bb.w;

    if (out_split) {
        // out[:, :128] at n*HID + c, out[:, 128:] at Nn*HID + n*HID + (c-128)
        size_t off_ = (c0 < HID) ? ((size_t)n * HID + c0)
                                 : ((size_t)Nn * HID + (size_t)n * HID + (c0 - HID));
        *(float4*)&out_split[off_] = o;
    } else {
        *(float4*)&h[(size_t)n * C_DIM + c0] = o;
        ushort4 ob;
        ob.x = (unsigned short)(__bfloat16_as_ushort(__float2bfloat16(o.x)));
        ob.y = (unsigned short)(__bfloat16_as_ushort(__float2bfloat16(o.y)));
        ob.z = (unsigned short)(__bfloat16_as_ushort(__float2bfloat16(o.z)));
        ob.w = (unsigned short)(__bfloat16_as_ushort(__float2bfloat16(o.w)));
        *(ushort4*)&((unsigned short*)hb)[(size_t)n * C_DIM + c0] = ob;
    }
}

// ---------------------------------------------------------------------------
// Host launch
// ---------------------------------------------------------------------------
extern "C" void kernel_launch(void* const* d_in, const int* in_sizes, int n_in,
                              void* d_out, int out_size, void* d_ws, size_t ws_size,
                              hipStream_t stream)
{
    const float* hf       = (const float*)d_in[0];
    const float* hs       = (const float*)d_in[1];
    const int*   edge     = (const int*)  d_in[2];
    const float* W        = (const float*)d_in[3];
    const float* att_src  = (const float*)d_in[4];
    const float* att_dst  = (const float*)d_in[5];
    const float* gat_b    = (const float*)d_in[6];
    const float* w1       = (const float*)d_in[7];
    const float* b1       = (const float*)d_in[8];
    const float* w2       = (const float*)d_in[9];
    const float* b2       = (const float*)d_in[10];
    const float* ln1g     = (const float*)d_in[11];
    const float* ln1b     = (const float*)d_in[12];
    const float* ln2g     = (const float*)d_in[13];
    const float* ln2b     = (const float*)d_in[14];
    float* out = (float*)d_out;

    const int N = in_sizes[0] / HID;       // 20000
    const int E = in_sizes[2] / 2;         // 320000
    const int* e_src = edge;
    const int* e_dst = edge + E;

    char* p = (char*)d_ws;
    auto alloc = [&](size_t bytes) {
        char* r = p;
        p += (bytes + 255) & ~(size_t)255;
        return (void*)r;
    };
    float*          h      = (float*)alloc((size_t)N * C_DIM * 4);
    __hip_bfloat16* hb     = (__hip_bfloat16*)alloc((size_t)N * C_DIM * 2);
    __hip_bfloat16* xhb    = (__hip_bfloat16*)alloc((size_t)N * C_DIM * 2);  // gemm1 out
    __hip_bfloat16* fbuf   = (__hip_bfloat16*)alloc((size_t)N * C_DIM * 2);  // gemm3 out
    __hip_bfloat16* midb   = (__hip_bfloat16*)alloc((size_t)N * FF_DIM * 2);
    float*          a_s    = (float*)alloc((size_t)N * HEADS * 4);
    float*          a_d    = (float*)alloc((size_t)N * HEADS * 4);
    float*          wexp   = (float*)alloc((size_t)E * HEADS * 4);
    int*            counts = (int*)alloc((size_t)N * 4);
    int*            offs   = (int*)alloc((size_t)(N + 1) * 4);
    int*            cursor = (int*)alloc((size_t)N * 4);
    int*            csr    = (int*)alloc((size_t)E * 4);
    int*            csrd   = (int*)alloc((size_t)E * 4);
    __hip_bfloat16* WT     = (__hip_bfloat16*)alloc((size_t)NLAYERS * C_DIM * C_DIM * 2);
    __hip_bfloat16* w1T    = (__hip_bfloat16*)alloc((size_t)NLAYERS * C_DIM * FF_DIM * 2);
    __hip_bfloat16* w2T    = (__hip_bfloat16*)alloc((size_t)NLAYERS * FF_DIM * C_DIM * 2);

    {
        int total = N * C_DIM;
        concat_kernel<<<(total + 255) / 256, 256, 0, stream>>>(hf, hs, h, hb, N);
    }
    transp_bf16_kernel<<<dim3(C_DIM / 32, C_DIM / 32, NLAYERS), 256, 0, stream>>>(W, WT, C_DIM, C_DIM);
    transp_bf16_kernel<<<dim3(FF_DIM / 32, C_DIM / 32, NLAYERS), 256, 0, stream>>>(w1, w1T, C_DIM, FF_DIM);
    transp_bf16_kernel<<<dim3(C_DIM / 32, FF_DIM / 32, NLAYERS), 256, 0, stream>>>(w2, w2T, FF_DIM, C_DIM);

    zero_i32_kernel<<<(N + 255) / 256, 256, 0, stream>>>(counts, N);
    hist_kernel<<<(E + 255) / 256, 256, 0, stream>>>(e_dst, counts, E);
    scan_kernel<<<1, 1024, 0, stream>>>(counts, offs, cursor, N);
    fill_kernel<<<(E + 255) / 256, 256, 0, stream>>>(e_src, e_dst, cursor, csr, csrd, E);

    const int gm = (N + BM - 1) / BM;   // 157

    for (int l = 0; l < NLAYERS; ++l) {
        const __hip_bfloat16* Wl  = WT  + (size_t)l * C_DIM * C_DIM;
        const __hip_bfloat16* w1l = w1T + (size_t)l * C_DIM * FF_DIM;
        const __hip_bfloat16* w2l = w2T + (size_t)l * FF_DIM * C_DIM;
        const float* asl  = att_src + (size_t)l * C_DIM;
        const float* adl  = att_dst + (size_t)l * C_DIM;
        const float* gbl  = gat_b + (size_t)l * C_DIM;
        const float* b1l  = b1 + (size_t)l * FF_DIM;
        const float* b2l  = b2 + (size_t)l * C_DIM;
        const float* g1l  = ln1g + (size_t)l * C_DIM;
        const float* be1l = ln1b + (size_t)l * C_DIM;
        const float* g2l  = ln2g + (size_t)l * C_DIM;
        const float* be2l = ln2b + (size_t)l * C_DIM;

        // xhb = h @ W[l] (bf16 out) + fused a_s/a_d epilogue
        gemm_bf16_kernel<<<dim3(gm, C_DIM / BN), 256, 0, stream>>>(
            hb, Wl, nullptr, nullptr, xhb, asl, adl, a_s, a_d, N, C_DIM, C_DIM, 0);
        // per-edge exp weights
        wexp_kernel<<<(E + 255) / 256, 256, 0, stream>>>(csr, csrd, a_s, a_d, wexp, E);
        // fused softmax-agg + bias + residual + LN1 (h, hb in place)
        agg_kernel<<<(N + 3) / 4, 256, 0, stream>>>(
            xhb, a_s, a_d, csr, offs, wexp, gbl, g1l, be1l, h, hb, N);
        // mid = relu(h @ w1 + b1)  (bf16 out)
        gemm_bf16_kernel<<<dim3(gm, FF_DIM / BN), 256, 0, stream>>>(
            hb, w1l, b1l, nullptr, midb, nullptr, nullptr, nullptr, nullptr,
            N, FF_DIM, C_DIM, 1);
        // fbuf = mid @ w2 + b2  (bf16 out)
        gemm_bf16_kernel<<<dim3(gm, C_DIM / BN), 256, 0, stream>>>(
            midb, w2l, b2l, nullptr, fbuf, nullptr, nullptr, nullptr, nullptr,
            N, C_DIM, FF_DIM, 0);
        // h = LN(fbuf + h); final layer writes split output directly
        ln2_kernel<<<(N + 3) / 4, 256, 0, stream>>>(
            fbuf, g2l, be2l, h, hb, (l == NLAYERS - 1) ? out : nullptr, N);
    }
}

// Round 5
// 1299.591 us; speedup vs baseline: 3.0460x; 1.1417x over previous
//
#include <hip/hip_runtime.h>
#include <hip/hip_bf16.h>
#include <math.h>

// Problem dims (fixed by reference)
#define C_DIM 256      // h width
#define HID 128
#define HEADS 4
#define OC 64          // per-head out channels
#define FF_DIM 512
#define NLAYERS 12

constexpr float LN_EPS = 1e-5f;
constexpr float SLOPE  = 0.2f;

typedef __attribute__((ext_vector_type(4))) float f32x4;
typedef __attribute__((ext_vector_type(8))) short bf16x8_t;
typedef __attribute__((ext_vector_type(4))) int i32x4;

__device__ __forceinline__ float leaky(float x) { return x > 0.f ? x : SLOPE * x; }

__device__ __forceinline__ float bf2f(unsigned short u) {
    union { unsigned i; float f; } v; v.i = ((unsigned)u) << 16; return v.f;
}

// ---------------------------------------------------------------------------
// Small utility kernels
// ---------------------------------------------------------------------------
__global__ void zero_i32_kernel(int* __restrict__ p, int n) {
    int i = blockIdx.x * blockDim.x + threadIdx.x;
    if (i < n) p[i] = 0;
}

__global__ void concat_kernel(const float* __restrict__ hf, const float* __restrict__ hs,
                              float* __restrict__ h, __hip_bfloat16* __restrict__ hb, int Nn) {
    int idx = blockIdx.x * blockDim.x + threadIdx.x;
    int total = Nn * C_DIM;
    if (idx < total) {
        int n = idx >> 8;
        int c = idx & 255;
        float v = (c < HID) ? hf[n * HID + c] : hs[n * HID + (c - HID)];
        h[idx] = v;
        hb[idx] = __float2bfloat16(v);
    }
}

// Transpose + convert weights: in [L][K][N] fp32 -> out [L][N][K] bf16
__global__ void transp_bf16_kernel(const float* __restrict__ in,
                                   __hip_bfloat16* __restrict__ out, int K, int N) {
    __shared__ float t[32][33];
    const float* inl = in + (size_t)blockIdx.z * K * N;
    __hip_bfloat16* outl = out + (size_t)blockIdx.z * K * N;
    int kb = blockIdx.y * 32, nb = blockIdx.x * 32;
    int tx = threadIdx.x & 31, ty = threadIdx.x >> 5; // 32x8
    #pragma unroll
    for (int r = 0; r < 32; r += 8)
        t[ty + r][tx] = inl[(size_t)(kb + ty + r) * N + nb + tx];
    __syncthreads();
    #pragma unroll
    for (int r = 0; r < 32; r += 8)
        outl[(size_t)(nb + ty + r) * K + kb + tx] = __float2bfloat16(t[tx][ty + r]);
}

// ---------------------------------------------------------------------------
// CSR build: histogram of dst, exclusive scan (wave-shuffle), fill src lists
// ---------------------------------------------------------------------------
__global__ void hist_kernel(const int* __restrict__ dst, int* __restrict__ counts, int E) {
    int e = blockIdx.x * blockDim.x + threadIdx.x;
    if (e < E) atomicAdd(&counts[dst[e]], 1);
}

// single block, 1024 threads = 16 waves. Wave shuffle scan + serial wave-sum scan.
__global__ void scan_kernel(const int* __restrict__ counts, int* __restrict__ offsets,
                            int* __restrict__ cursor, int n) {
    __shared__ int wsum[16];
    __shared__ int carry_s;
    const int lane = threadIdx.x & 63, wid = threadIdx.x >> 6;
    if (threadIdx.x == 0) carry_s = 0;
    __syncthreads();
    for (int base = 0; base < n; base += 1024) {
        int i = base + (int)threadIdx.x;
        int v = (i < n) ? counts[i] : 0;
        int x = v;
        #pragma unroll
        for (int off = 1; off < 64; off <<= 1) {
            int t = __shfl_up(x, off);
            if (lane >= off) x += t;
        }
        if (lane == 63) wsum[wid] = x;
        __syncthreads();
        if (threadIdx.x == 0) {
            int acc = carry_s;
            #pragma unroll
            for (int w = 0; w < 16; ++w) { int t = wsum[w]; wsum[w] = acc; acc += t; }
            carry_s = acc;
        }
        __syncthreads();
        int excl = wsum[wid] + x - v;
        if (i < n) { offsets[i] = excl; cursor[i] = excl; }
        __syncthreads();
    }
    if (threadIdx.x == 0) offsets[n] = carry_s;
}

__global__ void fill_kernel(const int* __restrict__ src, const int* __restrict__ dst,
                            int* __restrict__ cursor, int* __restrict__ csr_src,
                            int* __restrict__ csr_dst, int E) {
    int e = blockIdx.x * blockDim.x + threadIdx.x;
    if (e < E) {
        int d = dst[e];
        int p = atomicAdd(&cursor[d], 1);
        csr_src[p] = src[e];
        csr_dst[p] = d;
    }
}

// ---------------------------------------------------------------------------
// Per-edge exp weights (no max-subtraction: logits bounded, validated R2/R3).
// ---------------------------------------------------------------------------
__global__ void wexp_kernel(const int* __restrict__ csr, const int* __restrict__ csr_dst,
                            const float* __restrict__ a_s, const float* __restrict__ a_d,
                            float* __restrict__ wexp, int E) {
    int i = blockIdx.x * blockDim.x + threadIdx.x;
    if (i >= E) return;
    int s = csr[i], d = csr_dst[i];
    float4 av = *(const float4*)&a_s[(size_t)s * 4];
    float4 dv = *(const float4*)&a_d[(size_t)d * 4];
    float4 w;
    w.x = __expf(leaky(av.x + dv.x));
    w.y = __expf(leaky(av.y + dv.y));
    w.z = __expf(leaky(av.z + dv.z));
    w.w = __expf(leaky(av.w + dv.w));
    *(float4*)&wexp[(size_t)i * 4] = w;
}

// ---------------------------------------------------------------------------
// bf16 MFMA GEMM, occupancy-oriented: 64x64 tile, BK=64, 256 thr (2x2 waves,
// 32x32 per wave = 2x2 MFMA 16x16x32, acc 16 VGPR). Grid = (M/64)x(N/64):
// 1252+ blocks -> ~5 waves/SIMD (vs 1.2 at 128-tile; grid starvation fix).
// C/D: col=lane&15, row=(lane>>4)*4+reg  [verified m89/m91]
// Fused attention epilogue (aS non-null): BN=64 & col0 64-aligned => one
// block covers exactly one head's columns; cross-wave combine via LDS.
// ---------------------------------------------------------------------------
#define GBM 64
#define GBN 64
#define GBK 64
#define GLS 72   // LDS row stride (shorts): 144B; lanes map 2-way bank alias = free

__global__ __launch_bounds__(256) void gemm_bf16_kernel(
    const __hip_bfloat16* __restrict__ A,   // [M x K] bf16 row-major
    const __hip_bfloat16* __restrict__ BT,  // [N x K] bf16 row-major (B^T)
    const float* __restrict__ bias,         // [N] or null
    __hip_bfloat16* __restrict__ Cb,        // bf16 out
    const float* __restrict__ attS,         // [N] att_src slice or null
    const float* __restrict__ attD,
    float* __restrict__ aS,                 // [M x HEADS] out or null
    float* __restrict__ aD,
    int M, int N, int K, int relu)
{
    __shared__ short As[GBM * GLS];
    __shared__ short Bs[GBN * GLS];
    __shared__ float attP[2][2][GBM];       // [wn-half][s|d][row]
    const int tid = threadIdx.x;
    const int wave = tid >> 6, lane = tid & 63;
    const int lr = lane & 15, lq = lane >> 4;
    const int wm = (wave >> 1) * 32, wn = (wave & 1) * 32;
    const int row0 = blockIdx.x * GBM, col0 = blockIdx.y * GBN;

    const int sr = tid >> 2;              // staging row 0..63
    const int sc = (tid & 3) * 16;        // staging col (shorts): 0,16,32,48

    f32x4 acc[2][2] = {};

    for (int k0 = 0; k0 < K; k0 += GBK) {
        int gr = row0 + sr;
        i32x4 va0 = {}, va1 = {};
        if (gr < M) {
            const __hip_bfloat16* ap = &A[(size_t)gr * K + k0 + sc];
            va0 = *(const i32x4*)ap;
            va1 = *(const i32x4*)(ap + 8);
        }
        *(i32x4*)&As[sr * GLS + sc] = va0;
        *(i32x4*)&As[sr * GLS + sc + 8] = va1;
        const __hip_bfloat16* bp = &BT[(size_t)(col0 + sr) * K + k0 + sc];
        *(i32x4*)&Bs[sr * GLS + sc] = *(const i32x4*)bp;
        *(i32x4*)&Bs[sr * GLS + sc + 8] = *(const i32x4*)(bp + 8);
        __syncthreads();

        #pragma unroll
        for (int ks = 0; ks < 2; ++ks) {
            bf16x8_t af[2], bfr[2];
            #pragma unroll
            for (int t = 0; t < 2; ++t) {
                af[t]  = *(const bf16x8_t*)&As[(wm + t * 16 + lr) * GLS + ks * 32 + lq * 8];
                bfr[t] = *(const bf16x8_t*)&Bs[(wn + t * 16 + lr) * GLS + ks * 32 + lq * 8];
            }
            #pragma unroll
            for (int mt = 0; mt < 2; ++mt)
                #pragma unroll
                for (int nt = 0; nt < 2; ++nt)
                    acc[mt][nt] = __builtin_amdgcn_mfma_f32_16x16x32_bf16(
                        af[mt], bfr[nt], acc[mt][nt], 0, 0, 0);
        }
        __syncthreads();
    }

    float bv[2];
    #pragma unroll
    for (int nt = 0; nt < 2; ++nt)
        bv[nt] = bias ? bias[col0 + wn + nt * 16 + lr] : 0.f;

    #pragma unroll
    for (int mt = 0; mt < 2; ++mt) {
        #pragma unroll
        for (int r = 0; r < 4; ++r) {
            int grow = row0 + wm + mt * 16 + lq * 4 + r;
            if (grow >= M) continue;
            #pragma unroll
            for (int nt = 0; nt < 2; ++nt) {
                float v = acc[mt][nt][r] + bv[nt];
                if (relu) v = fmaxf(v, 0.f);
                Cb[(size_t)grow * N + col0 + wn + nt * 16 + lr] = __float2bfloat16(v);
            }
        }
    }

    // Fused attention-coefficient epilogue (gemm1 only)
    if (aS) {
        const int head = col0 >> 6;        // block covers one head (BN=64)
        float atS[2], atD[2];
        #pragma unroll
        for (int nt = 0; nt < 2; ++nt) {
            int c = col0 + wn + nt * 16 + lr;
            atS[nt] = attS[c];
            atD[nt] = attD[c];
        }
        #pragma unroll
        for (int mt = 0; mt < 2; ++mt) {
            #pragma unroll
            for (int r = 0; r < 4; ++r) {
                float vs = acc[mt][0][r] * atS[0] + acc[mt][1][r] * atS[1];
                float vd = acc[mt][0][r] * atD[0] + acc[mt][1][r] * atD[1];
                #pragma unroll
                for (int off = 1; off < 16; off <<= 1) {
                    vs += __shfl_xor(vs, off);
                    vd += __shfl_xor(vd, off);
                }
                if (lr == 0) {
                    int rl = wm + mt * 16 + lq * 4 + r;
                    attP[wave & 1][0][rl] = vs;
                    attP[wave & 1][1][rl] = vd;
                }
            }
        }
        __syncthreads();
        if (tid < GBM) {
            int grow = row0 + tid;
            if (grow < M) {
                aS[grow * HEADS + head] = attP[0][0][tid] + attP[1][0][tid];
                aD[grow * HEADS + head] = attP[0][1][tid] + attP[1][1][tid];
            }
        }
    }
}

// ---------------------------------------------------------------------------
// Fused GAT aggregation + bias + residual + LN1.
// One WAVE per node; node index forced wave-uniform (readfirstlane) so
// offs/csr reads become scalar loads. Lane owns 4 channels (8B gathers).
// ---------------------------------------------------------------------------
__global__ __launch_bounds__(256) void agg_kernel(
    const __hip_bfloat16* __restrict__ xhb, const float* __restrict__ a_s,
    const float* __restrict__ a_d, const int* __restrict__ csr,
    const int* __restrict__ offs, const float* __restrict__ wexp,
    const float* __restrict__ gat_b, const float* __restrict__ ln_g,
    const float* __restrict__ ln_b, float* __restrict__ h,
    __hip_bfloat16* __restrict__ hb, int Nn)
{
    const int lane = threadIdx.x & 63;
    const int n = __builtin_amdgcn_readfirstlane(blockIdx.x * 4 + (threadIdx.x >> 6));
    if (n >= Nn) return;
    const int head = lane >> 4;
    const int c0 = lane * 4;
    const unsigned short* x = (const unsigned short*)xhb;

    float4 res = *(const float4*)&h[(size_t)n * C_DIM + c0];

    float wself = __expf(leaky(a_s[n * 4 + head] + a_d[n * 4 + head]));
    ushort4 xs = *(const ushort4*)&x[(size_t)n * C_DIM + c0];
    float acc0[4], acc1[4] = {}, acc2[4] = {}, acc3[4] = {};
    acc0[0] = wself * bf2f(xs.x);
    acc0[1] = wself * bf2f(xs.y);
    acc0[2] = wself * bf2f(xs.z);
    acc0[3] = wself * bf2f(xs.w);
    float z = wself;

    const int beg = offs[n], end = offs[n + 1];
    int i = beg;
    for (; i + 4 <= end; i += 4) {
        int s0 = csr[i], s1 = csr[i + 1], s2 = csr[i + 2], s3 = csr[i + 3];
        float w0 = wexp[(size_t)(i + 0) * 4 + head];
        float w1 = wexp[(size_t)(i + 1) * 4 + head];
        float w2 = wexp[(size_t)(i + 2) * 4 + head];
        float w3 = wexp[(size_t)(i + 3) * 4 + head];
        ushort4 x0 = *(const ushort4*)&x[(size_t)s0 * C_DIM + c0];
        ushort4 x1 = *(const ushort4*)&x[(size_t)s1 * C_DIM + c0];
        ushort4 x2 = *(const ushort4*)&x[(size_t)s2 * C_DIM + c0];
        ushort4 x3 = *(const ushort4*)&x[(size_t)s3 * C_DIM + c0];
        acc0[0] += w0 * bf2f(x0.x); acc0[1] += w0 * bf2f(x0.y);
        acc0[2] += w0 * bf2f(x0.z); acc0[3] += w0 * bf2f(x0.w);
        acc1[0] += w1 * bf2f(x1.x); acc1[1] += w1 * bf2f(x1.y);
        acc1[2] += w1 * bf2f(x1.z); acc1[3] += w1 * bf2f(x1.w);
        acc2[0] += w2 * bf2f(x2.x); acc2[1] += w2 * bf2f(x2.y);
        acc2[2] += w2 * bf2f(x2.z); acc2[3] += w2 * bf2f(x2.w);
        acc3[0] += w3 * bf2f(x3.x); acc3[1] += w3 * bf2f(x3.y);
        acc3[2] += w3 * bf2f(x3.z); acc3[3] += w3 * bf2f(x3.w);
        z += (w0 + w1) + (w2 + w3);
    }
    for (; i < end; ++i) {
        int s0 = csr[i];
        float w0 = wexp[(size_t)i * 4 + head];
        ushort4 x0 = *(const ushort4*)&x[(size_t)s0 * C_DIM + c0];
        acc0[0] += w0 * bf2f(x0.x); acc0[1] += w0 * bf2f(x0.y);
        acc0[2] += w0 * bf2f(x0.z); acc0[3] += w0 * bf2f(x0.w);
        z += w0;
    }

    float4 gb = *(const float4*)&gat_b[c0];
    float rz = 1.0f / z;
    float val[4];
    val[0] = (acc0[0] + acc1[0] + acc2[0] + acc3[0]) * rz + gb.x + res.x;
    val[1] = (acc0[1] + acc1[1] + acc2[1] + acc3[1]) * rz + gb.y + res.y;
    val[2] = (acc0[2] + acc1[2] + acc2[2] + acc3[2]) * rz + gb.z + res.z;
    val[3] = (acc0[3] + acc1[3] + acc2[3] + acc3[3]) * rz + gb.w + res.w;

    float s1 = (val[0] + val[1]) + (val[2] + val[3]);
    float s2 = (val[0] * val[0] + val[1] * val[1]) + (val[2] * val[2] + val[3] * val[3]);
    #pragma unroll
    for (int off = 1; off < 64; off <<= 1) {
        s1 += __shfl_xor(s1, off);
        s2 += __shfl_xor(s2, off);
    }
    float mean = s1 * (1.0f / C_DIM);
    float inv = rsqrtf(s2 * (1.0f / C_DIM) - mean * mean + LN_EPS);
    float4 g = *(const float4*)&ln_g[c0];
    float4 bb = *(const float4*)&ln_b[c0];
    float4 o;
    o.x = (val[0] - mean) * inv * g.x + bb.x;
    o.y = (val[1] - mean) * inv * g.y + bb.y;
    o.z = (val[2] - mean) * inv * g.z + bb.z;
    o.w = (val[3] - mean) * inv * g.w + bb.w;
    *(float4*)&h[(size_t)n * C_DIM + c0] = o;
    ushort4 ob;
    ob.x = __bfloat16_as_ushort(__float2bfloat16(o.x));
    ob.y = __bfloat16_as_ushort(__float2bfloat16(o.y));
    ob.z = __bfloat16_as_ushort(__float2bfloat16(o.z));
    ob.w = __bfloat16_as_ushort(__float2bfloat16(o.w));
    *(ushort4*)&((unsigned short*)hb)[(size_t)n * C_DIM + c0] = ob;
}

// ---------------------------------------------------------------------------
// ln2: val = bf2f(fb) + h; LN; writes h+hb, or (final layer) split fp32 out.
// ---------------------------------------------------------------------------
__global__ __launch_bounds__(256) void ln2_kernel(
    const __hip_bfloat16* __restrict__ fb, const float* __restrict__ ln_g,
    const float* __restrict__ ln_b, float* __restrict__ h,
    __hip_bfloat16* __restrict__ hb, float* __restrict__ out_split, int Nn)
{
    const int lane = threadIdx.x & 63;
    const int n = __builtin_amdgcn_readfirstlane(blockIdx.x * 4 + (threadIdx.x >> 6));
    if (n >= Nn) return;
    const int c0 = lane * 4;
    const unsigned short* f = (const unsigned short*)fb;

    float4 res = *(const float4*)&h[(size_t)n * C_DIM + c0];
    ushort4 fv = *(const ushort4*)&f[(size_t)n * C_DIM + c0];
    float val[4];
    val[0] = bf2f(fv.x) + res.x;
    val[1] = bf2f(fv.y) + res.y;
    val[2] = bf2f(fv.z) + res.z;
    val[3] = bf2f(fv.w) + res.w;

    float s1 = (val[0] + val[1]) + (val[2] + val[3]);
    float s2 = (val[0] * val[0] + val[1] * val[1]) + (val[2] * val[2] + val[3] * val[3]);
    #pragma unroll
    for (int off = 1; off < 64; off <<= 1) {
        s1 += __shfl_xor(s1, off);
        s2 += __shfl_xor(s2, off);
    }
    float mean = s1 * (1.0f / C_DIM);
    float inv = rsqrtf(s2 * (1.0f / C_DIM) - mean * mean + LN_EPS);
    float4 g = *(const float4*)&ln_g[c0];
    float4 bb = *(const float4*)&ln_b[c0];
    float4 o;
    o.x = (val[0] - mean) * inv * g.x + bb.x;
    o.y = (val[1] - mean) * inv * g.y + bb.y;
    o.z = (val[2] - mean) * inv * g.z + bb.z;
    o.w = (val[3] - mean) * inv * g.w + bb.w;

    if (out_split) {
        size_t off_ = (c0 < HID) ? ((size_t)n * HID + c0)
                                 : ((size_t)Nn * HID + (size_t)n * HID + (c0 - HID));
        *(float4*)&out_split[off_] = o;
    } else {
        *(float4*)&h[(size_t)n * C_DIM + c0] = o;
        ushort4 ob;
        ob.x = __bfloat16_as_ushort(__float2bfloat16(o.x));
        ob.y = __bfloat16_as_ushort(__float2bfloat16(o.y));
        ob.z = __bfloat16_as_ushort(__float2bfloat16(o.z));
        ob.w = __bfloat16_as_ushort(__float2bfloat16(o.w));
        *(ushort4*)&((unsigned short*)hb)[(size_t)n * C_DIM + c0] = ob;
    }
}

// ---------------------------------------------------------------------------
// Host launch
// ---------------------------------------------------------------------------
extern "C" void kernel_launch(void* const* d_in, const int* in_sizes, int n_in,
                              void* d_out, int out_size, void* d_ws, size_t ws_size,
                              hipStream_t stream)
{
    const float* hf       = (const float*)d_in[0];
    const float* hs       = (const float*)d_in[1];
    const int*   edge     = (const int*)  d_in[2];
    const float* W        = (const float*)d_in[3];
    const float* att_src  = (const float*)d_in[4];
    const float* att_dst  = (const float*)d_in[5];
    const float* gat_b    = (const float*)d_in[6];
    const float* w1       = (const float*)d_in[7];
    const float* b1       = (const float*)d_in[8];
    const float* w2       = (const float*)d_in[9];
    const float* b2       = (const float*)d_in[10];
    const float* ln1g     = (const float*)d_in[11];
    const float* ln1b     = (const float*)d_in[12];
    const float* ln2g     = (const float*)d_in[13];
    const float* ln2b     = (const float*)d_in[14];
    float* out = (float*)d_out;

    const int N = in_sizes[0] / HID;       // 20000
    const int E = in_sizes[2] / 2;         // 320000
    const int* e_src = edge;
    const int* e_dst = edge + E;

    char* p = (char*)d_ws;
    auto alloc = [&](size_t bytes) {
        char* r = p;
        p += (bytes + 255) & ~(size_t)255;
        return (void*)r;
    };
    float*          h      = (float*)alloc((size_t)N * C_DIM * 4);
    __hip_bfloat16* hb     = (__hip_bfloat16*)alloc((size_t)N * C_DIM * 2);
    __hip_bfloat16* xhb    = (__hip_bfloat16*)alloc((size_t)N * C_DIM * 2);  // gemm1 out
    __hip_bfloat16* fbuf   = (__hip_bfloat16*)alloc((size_t)N * C_DIM * 2);  // gemm3 out
    __hip_bfloat16* midb   = (__hip_bfloat16*)alloc((size_t)N * FF_DIM * 2);
    float*          a_s    = (float*)alloc((size_t)N * HEADS * 4);
    float*          a_d    = (float*)alloc((size_t)N * HEADS * 4);
    float*          wexp   = (float*)alloc((size_t)E * HEADS * 4);
    int*            counts = (int*)alloc((size_t)N * 4);
    int*            offs   = (int*)alloc((size_t)(N + 1) * 4);
    int*            cursor = (int*)alloc((size_t)N * 4);
    int*            csr    = (int*)alloc((size_t)E * 4);
    int*            csrd   = (int*)alloc((size_t)E * 4);
    __hip_bfloat16* WT     = (__hip_bfloat16*)alloc((size_t)NLAYERS * C_DIM * C_DIM * 2);
    __hip_bfloat16* w1T    = (__hip_bfloat16*)alloc((size_t)NLAYERS * C_DIM * FF_DIM * 2);
    __hip_bfloat16* w2T    = (__hip_bfloat16*)alloc((size_t)NLAYERS * FF_DIM * C_DIM * 2);

    {
        int total = N * C_DIM;
        concat_kernel<<<(total + 255) / 256, 256, 0, stream>>>(hf, hs, h, hb, N);
    }
    transp_bf16_kernel<<<dim3(C_DIM / 32, C_DIM / 32, NLAYERS), 256, 0, stream>>>(W, WT, C_DIM, C_DIM);
    transp_bf16_kernel<<<dim3(FF_DIM / 32, C_DIM / 32, NLAYERS), 256, 0, stream>>>(w1, w1T, C_DIM, FF_DIM);
    transp_bf16_kernel<<<dim3(C_DIM / 32, FF_DIM / 32, NLAYERS), 256, 0, stream>>>(w2, w2T, FF_DIM, C_DIM);

    zero_i32_kernel<<<(N + 255) / 256, 256, 0, stream>>>(counts, N);
    hist_kernel<<<(E + 255) / 256, 256, 0, stream>>>(e_dst, counts, E);
    scan_kernel<<<1, 1024, 0, stream>>>(counts, offs, cursor, N);
    fill_kernel<<<(E + 255) / 256, 256, 0, stream>>>(e_src, e_dst, cursor, csr, csrd, E);

    const int gm = (N + GBM - 1) / GBM;   // 313

    for (int l = 0; l < NLAYERS; ++l) {
        const __hip_bfloat16* Wl  = WT  + (size_t)l * C_DIM * C_DIM;
        const __hip_bfloat16* w1l = w1T + (size_t)l * C_DIM * FF_DIM;
        const __hip_bfloat16* w2l = w2T + (size_t)l * FF_DIM * C_DIM;
        const float* asl  = att_src + (size_t)l * C_DIM;
        const float* adl  = att_dst + (size_t)l * C_DIM;
        const float* gbl  = gat_b + (size_t)l * C_DIM;
        const float* b1l  = b1 + (size_t)l * FF_DIM;
        const float* b2l  = b2 + (size_t)l * C_DIM;
        const float* g1l  = ln1g + (size_t)l * C_DIM;
        const float* be1l = ln1b + (size_t)l * C_DIM;
        const float* g2l  = ln2g + (size_t)l * C_DIM;
        const float* be2l = ln2b + (size_t)l * C_DIM;

        // xhb = h @ W[l] (bf16 out) + fused a_s/a_d epilogue
        gemm_bf16_kernel<<<dim3(gm, C_DIM / GBN), 256, 0, stream>>>(
            hb, Wl, nullptr, xhb, asl, adl, a_s, a_d, N, C_DIM, C_DIM, 0);
        // per-edge exp weights
        wexp_kernel<<<(E + 255) / 256, 256, 0, stream>>>(csr, csrd, a_s, a_d, wexp, E);
        // fused softmax-agg + bias + residual + LN1 (h, hb in place)
        agg_kernel<<<(N + 3) / 4, 256, 0, stream>>>(
            xhb, a_s, a_d, csr, offs, wexp, gbl, g1l, be1l, h, hb, N);
        // mid = relu(h @ w1 + b1)  (bf16 out)
        gemm_bf16_kernel<<<dim3(gm, FF_DIM / GBN), 256, 0, stream>>>(
            hb, w1l, b1l, midb, nullptr, nullptr, nullptr, nullptr,
            N, FF_DIM, C_DIM, 1);
        // fbuf = mid @ w2 + b2  (bf16 out)
        gemm_bf16_kernel<<<dim3(gm, C_DIM / GBN), 256, 0, stream>>>(
            midb, w2l, b2l, fbuf, nullptr, nullptr, nullptr, nullptr,
            N, C_DIM, FF_DIM, 0);
        // h = LN(fbuf + h); final layer writes split output directly
        ln2_kernel<<<(N + 3) / 4, 256, 0, stream>>>(
            fbuf, g2l, be2l, h, hb, (l == NLAYERS - 1) ? out : nullptr, N);
    }
}

// Round 6
// 1264.472 us; speedup vs baseline: 3.1306x; 1.0278x over previous
//
#include <hip/hip_runtime.h>
#include <hip/hip_bf16.h>
#include <math.h>

// Problem dims (fixed by reference)
#define C_DIM 256      // h width
#define HID 128
#define HEADS 4
#define OC 64          // per-head out channels
#define FF_DIM 512
#define NLAYERS 12

constexpr float LN_EPS = 1e-5f;
constexpr float SLOPE  = 0.2f;

typedef __attribute__((ext_vector_type(4))) float f32x4;
typedef __attribute__((ext_vector_type(8))) short bf16x8_t;
typedef __attribute__((ext_vector_type(4))) int i32x4;

__device__ __forceinline__ float leaky(float x) { return x > 0.f ? x : SLOPE * x; }

__device__ __forceinline__ float bf2f(unsigned short u) {
    union { unsigned i; float f; } v; v.i = ((unsigned)u) << 16; return v.f;
}
// unpack packed pair of bf16 (one u32) -> two floats
__device__ __forceinline__ void bf2x(unsigned u, float& lo, float& hi) {
    union { unsigned i; float f; } a, b;
    a.i = u << 16; b.i = u & 0xffff0000u;
    lo = a.f; hi = b.f;
}
__device__ __forceinline__ unsigned packbf(float lo, float hi) {
    unsigned a = __bfloat16_as_ushort(__float2bfloat16(lo));
    unsigned b = __bfloat16_as_ushort(__float2bfloat16(hi));
    return a | (b << 16);
}

// ---------------------------------------------------------------------------
// Small utility kernels
// ---------------------------------------------------------------------------
__global__ void zero_i32_kernel(int* __restrict__ p, int n) {
    int i = blockIdx.x * blockDim.x + threadIdx.x;
    if (i < n) p[i] = 0;
}

__global__ void concat_kernel(const float* __restrict__ hf, const float* __restrict__ hs,
                              float* __restrict__ h, __hip_bfloat16* __restrict__ hb, int Nn) {
    int idx = blockIdx.x * blockDim.x + threadIdx.x;
    int total = Nn * C_DIM;
    if (idx < total) {
        int n = idx >> 8;
        int c = idx & 255;
        float v = (c < HID) ? hf[n * HID + c] : hs[n * HID + (c - HID)];
        h[idx] = v;
        hb[idx] = __float2bfloat16(v);
    }
}

// Transpose + convert weights: in [L][K][N] fp32 -> out [L][N][K] bf16
__global__ void transp_bf16_kernel(const float* __restrict__ in,
                                   __hip_bfloat16* __restrict__ out, int K, int N) {
    __shared__ float t[32][33];
    const float* inl = in + (size_t)blockIdx.z * K * N;
    __hip_bfloat16* outl = out + (size_t)blockIdx.z * K * N;
    int kb = blockIdx.y * 32, nb = blockIdx.x * 32;
    int tx = threadIdx.x & 31, ty = threadIdx.x >> 5; // 32x8
    #pragma unroll
    for (int r = 0; r < 32; r += 8)
        t[ty + r][tx] = inl[(size_t)(kb + ty + r) * N + nb + tx];
    __syncthreads();
    #pragma unroll
    for (int r = 0; r < 32; r += 8)
        outl[(size_t)(nb + ty + r) * K + kb + tx] = __float2bfloat16(t[tx][ty + r]);
}

// ---------------------------------------------------------------------------
// CSR build: histogram of dst, exclusive scan (wave-shuffle), fill src lists
// ---------------------------------------------------------------------------
__global__ void hist_kernel(const int* __restrict__ dst, int* __restrict__ counts, int E) {
    int e = blockIdx.x * blockDim.x + threadIdx.x;
    if (e < E) atomicAdd(&counts[dst[e]], 1);
}

// single block, 1024 threads = 16 waves. Wave shuffle scan + serial wave-sum scan.
__global__ void scan_kernel(const int* __restrict__ counts, int* __restrict__ offsets,
                            int* __restrict__ cursor, int n) {
    __shared__ int wsum[16];
    __shared__ int carry_s;
    const int lane = threadIdx.x & 63, wid = threadIdx.x >> 6;
    if (threadIdx.x == 0) carry_s = 0;
    __syncthreads();
    for (int base = 0; base < n; base += 1024) {
        int i = base + (int)threadIdx.x;
        int v = (i < n) ? counts[i] : 0;
        int x = v;
        #pragma unroll
        for (int off = 1; off < 64; off <<= 1) {
            int t = __shfl_up(x, off);
            if (lane >= off) x += t;
        }
        if (lane == 63) wsum[wid] = x;
        __syncthreads();
        if (threadIdx.x == 0) {
            int acc = carry_s;
            #pragma unroll
            for (int w = 0; w < 16; ++w) { int t = wsum[w]; wsum[w] = acc; acc += t; }
            carry_s = acc;
        }
        __syncthreads();
        int excl = wsum[wid] + x - v;
        if (i < n) { offsets[i] = excl; cursor[i] = excl; }
        __syncthreads();
    }
    if (threadIdx.x == 0) offsets[n] = carry_s;
}

__global__ void fill_kernel(const int* __restrict__ src, const int* __restrict__ dst,
                            int* __restrict__ cursor, int* __restrict__ csr_src, int E) {
    int e = blockIdx.x * blockDim.x + threadIdx.x;
    if (e < E) {
        int d = dst[e];
        int p = atomicAdd(&cursor[d], 1);
        csr_src[p] = src[e];
    }
}

// ---------------------------------------------------------------------------
// bf16 MFMA GEMM, occupancy-oriented: 64x64 tile, BK=64, 256 thr (2x2 waves,
// 32x32 per wave = 2x2 MFMA 16x16x32, acc 16 VGPR). Grid = (M/64)x(N/64).
// C/D: col=lane&15, row=(lane>>4)*4+reg  [verified m89/m91]
// Fused attention epilogue (aS non-null): BN=64 & col0 64-aligned => one
// block covers exactly one head's columns; cross-wave combine via LDS.
// ---------------------------------------------------------------------------
#define GBM 64
#define GBN 64
#define GBK 64
#define GLS 72   // LDS row stride (shorts): 144B; 2-way bank alias = free

__global__ __launch_bounds__(256) void gemm_bf16_kernel(
    const __hip_bfloat16* __restrict__ A,   // [M x K] bf16 row-major
    const __hip_bfloat16* __restrict__ BT,  // [N x K] bf16 row-major (B^T)
    const float* __restrict__ bias,         // [N] or null
    __hip_bfloat16* __restrict__ Cb,        // bf16 out
    const float* __restrict__ attS,         // [N] att_src slice or null
    const float* __restrict__ attD,
    float* __restrict__ aS,                 // [M x HEADS] out or null
    float* __restrict__ aD,
    int M, int N, int K, int relu)
{
    __shared__ short As[GBM * GLS];
    __shared__ short Bs[GBN * GLS];
    __shared__ float attP[2][2][GBM];       // [wn-half][s|d][row]
    const int tid = threadIdx.x;
    const int wave = tid >> 6, lane = tid & 63;
    const int lr = lane & 15, lq = lane >> 4;
    const int wm = (wave >> 1) * 32, wn = (wave & 1) * 32;
    const int row0 = blockIdx.x * GBM, col0 = blockIdx.y * GBN;

    const int sr = tid >> 2;              // staging row 0..63
    const int sc = (tid & 3) * 16;        // staging col (shorts): 0,16,32,48

    f32x4 acc[2][2] = {};

    for (int k0 = 0; k0 < K; k0 += GBK) {
        int gr = row0 + sr;
        i32x4 va0 = {}, va1 = {};
        if (gr < M) {
            const __hip_bfloat16* ap = &A[(size_t)gr * K + k0 + sc];
            va0 = *(const i32x4*)ap;
            va1 = *(const i32x4*)(ap + 8);
        }
        *(i32x4*)&As[sr * GLS + sc] = va0;
        *(i32x4*)&As[sr * GLS + sc + 8] = va1;
        const __hip_bfloat16* bp = &BT[(size_t)(col0 + sr) * K + k0 + sc];
        *(i32x4*)&Bs[sr * GLS + sc] = *(const i32x4*)bp;
        *(i32x4*)&Bs[sr * GLS + sc + 8] = *(const i32x4*)(bp + 8);
        __syncthreads();

        #pragma unroll
        for (int ks = 0; ks < 2; ++ks) {
            bf16x8_t af[2], bfr[2];
            #pragma unroll
            for (int t = 0; t < 2; ++t) {
                af[t]  = *(const bf16x8_t*)&As[(wm + t * 16 + lr) * GLS + ks * 32 + lq * 8];
                bfr[t] = *(const bf16x8_t*)&Bs[(wn + t * 16 + lr) * GLS + ks * 32 + lq * 8];
            }
            #pragma unroll
            for (int mt = 0; mt < 2; ++mt)
                #pragma unroll
                for (int nt = 0; nt < 2; ++nt)
                    acc[mt][nt] = __builtin_amdgcn_mfma_f32_16x16x32_bf16(
                        af[mt], bfr[nt], acc[mt][nt], 0, 0, 0);
        }
        __syncthreads();
    }

    float bv[2];
    #pragma unroll
    for (int nt = 0; nt < 2; ++nt)
        bv[nt] = bias ? bias[col0 + wn + nt * 16 + lr] : 0.f;

    #pragma unroll
    for (int mt = 0; mt < 2; ++mt) {
        #pragma unroll
        for (int r = 0; r < 4; ++r) {
            int grow = row0 + wm + mt * 16 + lq * 4 + r;
            if (grow >= M) continue;
            #pragma unroll
            for (int nt = 0; nt < 2; ++nt) {
                float v = acc[mt][nt][r] + bv[nt];
                if (relu) v = fmaxf(v, 0.f);
                Cb[(size_t)grow * N + col0 + wn + nt * 16 + lr] = __float2bfloat16(v);
            }
        }
    }

    // Fused attention-coefficient epilogue (gemm1 only)
    if (aS) {
        const int head = col0 >> 6;        // block covers one head (BN=64)
        float atS[2], atD[2];
        #pragma unroll
        for (int nt = 0; nt < 2; ++nt) {
            int c = col0 + wn + nt * 16 + lr;
            atS[nt] = attS[c];
            atD[nt] = attD[c];
        }
        #pragma unroll
        for (int mt = 0; mt < 2; ++mt) {
            #pragma unroll
            for (int r = 0; r < 4; ++r) {
                float vs = acc[mt][0][r] * atS[0] + acc[mt][1][r] * atS[1];
                float vd = acc[mt][0][r] * atD[0] + acc[mt][1][r] * atD[1];
                #pragma unroll
                for (int off = 1; off < 16; off <<= 1) {
                    vs += __shfl_xor(vs, off);
                    vd += __shfl_xor(vd, off);
                }
                if (lr == 0) {
                    int rl = wm + mt * 16 + lq * 4 + r;
                    attP[wave & 1][0][rl] = vs;
                    attP[wave & 1][1][rl] = vd;
                }
            }
        }
        __syncthreads();
        if (tid < GBM) {
            int grow = row0 + tid;
            if (grow < M) {
                aS[grow * HEADS + head] = attP[0][0][tid] + attP[1][0][tid];
                aD[grow * HEADS + head] = attP[0][1][tid] + attP[1][1][tid];
            }
        }
    }
}

// ---------------------------------------------------------------------------
// Fused GAT: per-edge exp weights computed in-loop + weighted bf16 gather +
// bias + residual + LN1. One WAVE per node; lane owns 8 channels (16B
// gathers) so 32 lanes cover a row -> the wave's two 32-lane halves process
// two disjoint edge subsets concurrently (half0: first ceil(ne/2) edges,
// half1: rest + self-loop); combined via shfl_xor(32). No LDS, no barriers.
// ---------------------------------------------------------------------------
__global__ __launch_bounds__(256) void agg_kernel(
    const __hip_bfloat16* __restrict__ xhb, const float* __restrict__ a_s,
    const float* __restrict__ a_d, const int* __restrict__ csr,
    const int* __restrict__ offs, const float* __restrict__ gat_b,
    const float* __restrict__ ln_g, const float* __restrict__ ln_b,
    float* __restrict__ h, __hip_bfloat16* __restrict__ hb, int Nn)
{
    const int lane = threadIdx.x & 63;
    const int n = __builtin_amdgcn_readfirstlane(blockIdx.x * 4 + (threadIdx.x >> 6));
    if (n >= Nn) return;
    const int half = lane >> 5;
    const int sl = lane & 31;
    const int head = sl >> 3;            // 8 lanes per head
    const int c0 = sl * 8;               // 8 channels per lane
    const unsigned* x = (const unsigned*)xhb;   // packed bf16 pairs
    const size_t rowp = (size_t)n * (C_DIM / 2) + (c0 >> 1);

    const float ad = a_d[n * 4 + head];

    const int beg = offs[n], end = offs[n + 1];
    const int ne = end - beg;
    const int nh0 = (ne + 1) >> 1;
    int ih  = half ? (beg + nh0) : beg;
    int cnt = half ? (ne - nh0) : nh0;

    float acc[8] = {};
    float z = 0.f;

    // self-loop handled by half 1
    {
        float wself = __expf(leaky(a_s[n * 4 + head] + ad));
        if (half) {
            i32x4 xv = *(const i32x4*)&x[rowp];
            #pragma unroll
            for (int q = 0; q < 4; ++q) {
                float lo, hi; bf2x((unsigned)xv[q], lo, hi);
                acc[2 * q]     = wself * lo;
                acc[2 * q + 1] = wself * hi;
            }
            z = wself;
        }
    }

    for (; cnt >= 4; cnt -= 4, ih += 4) {
        int s0 = csr[ih], s1 = csr[ih + 1], s2 = csr[ih + 2], s3 = csr[ih + 3];
        float w0 = __expf(leaky(a_s[s0 * 4 + head] + ad));
        float w1 = __expf(leaky(a_s[s1 * 4 + head] + ad));
        float w2 = __expf(leaky(a_s[s2 * 4 + head] + ad));
        float w3 = __expf(leaky(a_s[s3 * 4 + head] + ad));
        i32x4 x0 = *(const i32x4*)&x[(size_t)s0 * (C_DIM / 2) + (c0 >> 1)];
        i32x4 x1 = *(const i32x4*)&x[(size_t)s1 * (C_DIM / 2) + (c0 >> 1)];
        i32x4 x2 = *(const i32x4*)&x[(size_t)s2 * (C_DIM / 2) + (c0 >> 1)];
        i32x4 x3 = *(const i32x4*)&x[(size_t)s3 * (C_DIM / 2) + (c0 >> 1)];
        #pragma unroll
        for (int q = 0; q < 4; ++q) {
            float lo, hi;
            bf2x((unsigned)x0[q], lo, hi);
            acc[2 * q] += w0 * lo; acc[2 * q + 1] += w0 * hi;
            bf2x((unsigned)x1[q], lo, hi);
            acc[2 * q] += w1 * lo; acc[2 * q + 1] += w1 * hi;
            bf2x((unsigned)x2[q], lo, hi);
            acc[2 * q] += w2 * lo; acc[2 * q + 1] += w2 * hi;
            bf2x((unsigned)x3[q], lo, hi);
            acc[2 * q] += w3 * lo; acc[2 * q + 1] += w3 * hi;
        }
        z += (w0 + w1) + (w2 + w3);
    }
    for (; cnt > 0; --cnt, ++ih) {
        int s0 = csr[ih];
        float w0 = __expf(leaky(a_s[s0 * 4 + head] + ad));
        i32x4 x0 = *(const i32x4*)&x[(size_t)s0 * (C_DIM / 2) + (c0 >> 1)];
        #pragma unroll
        for (int q = 0; q < 4; ++q) {
            float lo, hi; bf2x((unsigned)x0[q], lo, hi);
            acc[2 * q] += w0 * lo; acc[2 * q + 1] += w0 * hi;
        }
        z += w0;
    }

    // combine the two halves
    #pragma unroll
    for (int j = 0; j < 8; ++j) acc[j] += __shfl_xor(acc[j], 32);
    z += __shfl_xor(z, 32);

    // bias + residual
    float4 res0 = *(const float4*)&h[(size_t)n * C_DIM + c0];
    float4 res1 = *(const float4*)&h[(size_t)n * C_DIM + c0 + 4];
    float4 gb0 = *(const float4*)&gat_b[c0];
    float4 gb1 = *(const float4*)&gat_b[c0 + 4];
    float rz = 1.0f / z;
    float val[8];
    val[0] = acc[0] * rz + gb0.x + res0.x;
    val[1] = acc[1] * rz + gb0.y + res0.y;
    val[2] = acc[2] * rz + gb0.z + res0.z;
    val[3] = acc[3] * rz + gb0.w + res0.w;
    val[4] = acc[4] * rz + gb1.x + res1.x;
    val[5] = acc[5] * rz + gb1.y + res1.y;
    val[6] = acc[6] * rz + gb1.z + res1.z;
    val[7] = acc[7] * rz + gb1.w + res1.w;

    // LN over 256 channels; each channel appears on 2 lanes (both halves),
    // so the 64-lane butterfly double-counts -> normalize by 512.
    float s1 = 0.f, s2 = 0.f;
    #pragma unroll
    for (int j = 0; j < 8; ++j) { s1 += val[j]; s2 += val[j] * val[j]; }
    #pragma unroll
    for (int off = 1; off < 64; off <<= 1) {
        s1 += __shfl_xor(s1, off);
        s2 += __shfl_xor(s2, off);
    }
    float mean = s1 * (1.0f / (2 * C_DIM));
    float inv = rsqrtf(s2 * (1.0f / (2 * C_DIM)) - mean * mean + LN_EPS);

    if (half == 0) {
        float4 g0 = *(const float4*)&ln_g[c0];
        float4 g1 = *(const float4*)&ln_g[c0 + 4];
        float4 bb0 = *(const float4*)&ln_b[c0];
        float4 bb1 = *(const float4*)&ln_b[c0 + 4];
        float o[8];
        o[0] = (val[0] - mean) * inv * g0.x + bb0.x;
        o[1] = (val[1] - mean) * inv * g0.y + bb0.y;
        o[2] = (val[2] - mean) * inv * g0.z + bb0.z;
        o[3] = (val[3] - mean) * inv * g0.w + bb0.w;
        o[4] = (val[4] - mean) * inv * g1.x + bb1.x;
        o[5] = (val[5] - mean) * inv * g1.y + bb1.y;
        o[6] = (val[6] - mean) * inv * g1.z + bb1.z;
        o[7] = (val[7] - mean) * inv * g1.w + bb1.w;
        float4 o0 = {o[0], o[1], o[2], o[3]};
        float4 o1 = {o[4], o[5], o[6], o[7]};
        *(float4*)&h[(size_t)n * C_DIM + c0] = o0;
        *(float4*)&h[(size_t)n * C_DIM + c0 + 4] = o1;
        i32x4 ob;
        ob[0] = (int)packbf(o[0], o[1]);
        ob[1] = (int)packbf(o[2], o[3]);
        ob[2] = (int)packbf(o[4], o[5]);
        ob[3] = (int)packbf(o[6], o[7]);
        *(i32x4*)&((unsigned*)hb)[rowp] = ob;
    }
}

// ---------------------------------------------------------------------------
// ln2: val = bf2f(fb) + h; LN; writes h+hb, or (final layer) split fp32 out.
// ---------------------------------------------------------------------------
__global__ __launch_bounds__(256) void ln2_kernel(
    const __hip_bfloat16* __restrict__ fb, const float* __restrict__ ln_g,
    const float* __restrict__ ln_b, float* __restrict__ h,
    __hip_bfloat16* __restrict__ hb, float* __restrict__ out_split, int Nn)
{
    const int lane = threadIdx.x & 63;
    const int n = __builtin_amdgcn_readfirstlane(blockIdx.x * 4 + (threadIdx.x >> 6));
    if (n >= Nn) return;
    const int c0 = lane * 4;
    const unsigned short* f = (const unsigned short*)fb;

    float4 res = *(const float4*)&h[(size_t)n * C_DIM + c0];
    ushort4 fv = *(const ushort4*)&f[(size_t)n * C_DIM + c0];
    float val[4];
    val[0] = bf2f(fv.x) + res.x;
    val[1] = bf2f(fv.y) + res.y;
    val[2] = bf2f(fv.z) + res.z;
    val[3] = bf2f(fv.w) + res.w;

    float s1 = (val[0] + val[1]) + (val[2] + val[3]);
    float s2 = (val[0] * val[0] + val[1] * val[1]) + (val[2] * val[2] + val[3] * val[3]);
    #pragma unroll
    for (int off = 1; off < 64; off <<= 1) {
        s1 += __shfl_xor(s1, off);
        s2 += __shfl_xor(s2, off);
    }
    float mean = s1 * (1.0f / C_DIM);
    float inv = rsqrtf(s2 * (1.0f / C_DIM) - mean * mean + LN_EPS);
    float4 g = *(const float4*)&ln_g[c0];
    float4 bb = *(const float4*)&ln_b[c0];
    float4 o;
    o.x = (val[0] - mean) * inv * g.x + bb.x;
    o.y = (val[1] - mean) * inv * g.y + bb.y;
    o.z = (val[2] - mean) * inv * g.z + bb.z;
    o.w = (val[3] - mean) * inv * g.w + bb.w;

    if (out_split) {
        size_t off_ = (c0 < HID) ? ((size_t)n * HID + c0)
                                 : ((size_t)Nn * HID + (size_t)n * HID + (c0 - HID));
        *(float4*)&out_split[off_] = o;
    } else {
        *(float4*)&h[(size_t)n * C_DIM + c0] = o;
        ushort4 ob;
        ob.x = __bfloat16_as_ushort(__float2bfloat16(o.x));
        ob.y = __bfloat16_as_ushort(__float2bfloat16(o.y));
        ob.z = __bfloat16_as_ushort(__float2bfloat16(o.z));
        ob.w = __bfloat16_as_ushort(__float2bfloat16(o.w));
        *(ushort4*)&((unsigned short*)hb)[(size_t)n * C_DIM + c0] = ob;
    }
}

// ---------------------------------------------------------------------------
// Host launch
// ---------------------------------------------------------------------------
extern "C" void kernel_launch(void* const* d_in, const int* in_sizes, int n_in,
                              void* d_out, int out_size, void* d_ws, size_t ws_size,
                              hipStream_t stream)
{
    const float* hf       = (const float*)d_in[0];
    const float* hs       = (const float*)d_in[1];
    const int*   edge     = (const int*)  d_in[2];
    const float* W        = (const float*)d_in[3];
    const float* att_src  = (const float*)d_in[4];
    const float* att_dst  = (const float*)d_in[5];
    const float* gat_b    = (const float*)d_in[6];
    const float* w1       = (const float*)d_in[7];
    const float* b1       = (const float*)d_in[8];
    const float* w2       = (const float*)d_in[9];
    const float* b2       = (const float*)d_in[10];
    const float* ln1g     = (const float*)d_in[11];
    const float* ln1b     = (const float*)d_in[12];
    const float* ln2g     = (const float*)d_in[13];
    const float* ln2b     = (const float*)d_in[14];
    float* out = (float*)d_out;

    const int N = in_sizes[0] / HID;       // 20000
    const int E = in_sizes[2] / 2;         // 320000
    const int* e_src = edge;
    const int* e_dst = edge + E;

    char* p = (char*)d_ws;
    auto alloc = [&](size_t bytes) {
        char* r = p;
        p += (bytes + 255) & ~(size_t)255;
        return (void*)r;
    };
    float*          h      = (float*)alloc((size_t)N * C_DIM * 4);
    __hip_bfloat16* hb     = (__hip_bfloat16*)alloc((size_t)N * C_DIM * 2);
    __hip_bfloat16* xhb    = (__hip_bfloat16*)alloc((size_t)N * C_DIM * 2);  // gemm1 out
    __hip_bfloat16* fbuf   = (__hip_bfloat16*)alloc((size_t)N * C_DIM * 2);  // gemm3 out
    __hip_bfloat16* midb   = (__hip_bfloat16*)alloc((size_t)N * FF_DIM * 2);
    float*          a_s    = (float*)alloc((size_t)N * HEADS * 4);
    float*          a_d    = (float*)alloc((size_t)N * HEADS * 4);
    int*            counts = (int*)alloc((size_t)N * 4);
    int*            offs   = (int*)alloc((size_t)(N + 1) * 4);
    int*            cursor = (int*)alloc((size_t)N * 4);
    int*            csr    = (int*)alloc((size_t)E * 4);
    __hip_bfloat16* WT     = (__hip_bfloat16*)alloc((size_t)NLAYERS * C_DIM * C_DIM * 2);
    __hip_bfloat16* w1T    = (__hip_bfloat16*)alloc((size_t)NLAYERS * C_DIM * FF_DIM * 2);
    __hip_bfloat16* w2T    = (__hip_bfloat16*)alloc((size_t)NLAYERS * FF_DIM * C_DIM * 2);

    {
        int total = N * C_DIM;
        concat_kernel<<<(total + 255) / 256, 256, 0, stream>>>(hf, hs, h, hb, N);
    }
    transp_bf16_kernel<<<dim3(C_DIM / 32, C_DIM / 32, NLAYERS), 256, 0, stream>>>(W, WT, C_DIM, C_DIM);
    transp_bf16_kernel<<<dim3(FF_DIM / 32, C_DIM / 32, NLAYERS), 256, 0, stream>>>(w1, w1T, C_DIM, FF_DIM);
    transp_bf16_kernel<<<dim3(C_DIM / 32, FF_DIM / 32, NLAYERS), 256, 0, stream>>>(w2, w2T, FF_DIM, C_DIM);

    zero_i32_kernel<<<(N + 255) / 256, 256, 0, stream>>>(counts, N);
    hist_kernel<<<(E + 255) / 256, 256, 0, stream>>>(e_dst, counts, E);
    scan_kernel<<<1, 1024, 0, stream>>>(counts, offs, cursor, N);
    fill_kernel<<<(E + 255) / 256, 256, 0, stream>>>(e_src, e_dst, cursor, csr, E);

    const int gm = (N + GBM - 1) / GBM;   // 313

    for (int l = 0; l < NLAYERS; ++l) {
        const __hip_bfloat16* Wl  = WT  + (size_t)l * C_DIM * C_DIM;
        const __hip_bfloat16* w1l = w1T + (size_t)l * C_DIM * FF_DIM;
        const __hip_bfloat16* w2l = w2T + (size_t)l * FF_DIM * C_DIM;
        const float* asl  = att_src + (size_t)l * C_DIM;
        const float* adl  = att_dst + (size_t)l * C_DIM;
        const float* gbl  = gat_b + (size_t)l * C_DIM;
        const float* b1l  = b1 + (size_t)l * FF_DIM;
        const float* b2l  = b2 + (size_t)l * C_DIM;
        const float* g1l  = ln1g + (size_t)l * C_DIM;
        const float* be1l = ln1b + (size_t)l * C_DIM;
        const float* g2l  = ln2g + (size_t)l * C_DIM;
        const float* be2l = ln2b + (size_t)l * C_DIM;

        // xhb = h @ W[l] (bf16 out) + fused a_s/a_d epilogue
        gemm_bf16_kernel<<<dim3(gm, C_DIM / GBN), 256, 0, stream>>>(
            hb, Wl, nullptr, xhb, asl, adl, a_s, a_d, N, C_DIM, C_DIM, 0);
        // fused exp-weights + softmax-agg + bias + residual + LN1 (h, hb in place)
        agg_kernel<<<(N + 3) / 4, 256, 0, stream>>>(
            xhb, a_s, a_d, csr, offs, gbl, g1l, be1l, h, hb, N);
        // mid = relu(h @ w1 + b1)  (bf16 out)
        gemm_bf16_kernel<<<dim3(gm, FF_DIM / GBN), 256, 0, stream>>>(
            hb, w1l, b1l, midb, nullptr, nullptr, nullptr, nullptr,
            N, FF_DIM, C_DIM, 1);
        // fbuf = mid @ w2 + b2  (bf16 out)
        gemm_bf16_kernel<<<dim3(gm, C_DIM / GBN), 256, 0, stream>>>(
            midb, w2l, b2l, fbuf, nullptr, nullptr, nullptr, nullptr,
            N, C_DIM, FF_DIM, 0);
        // h = LN(fbuf + h); final layer writes split output directly
        ln2_kernel<<<(N + 3) / 4, 256, 0, stream>>>(
            fbuf, g2l, be2l, h, hb, (l == NLAYERS - 1) ? out : nullptr, N);
    }
}